// Round 12
// 660.894 us; speedup vs baseline: 1.7242x; 1.0503x over previous
//
#include <hip/hip_runtime.h>
#include <math.h>

#define NN 2048
#define NB 8
#define FF 256
#define HH 128
#define KSEL 1025
#define NROWS (NB*NN)
#define MPAD 1152
#define MC (MPAD*NB)
#define LMAX 64
// sparseA2 tiling
#define MI 6
#define RSTRIDE 2052
#define ZIDX 2048
#define LP 72

typedef unsigned short ushort_t;
typedef __attribute__((ext_vector_type(8))) short short8;
typedef __attribute__((ext_vector_type(4))) float f32x4;

__device__ inline ushort_t f2bf(float f) {
  unsigned u = __float_as_uint(f);
  unsigned r = (u + 0x7FFFu + ((u >> 16) & 1u)) >> 16;
  return (ushort_t)r;
}
__device__ inline float bf2f(ushort_t u) {
  unsigned x = ((unsigned)u) << 16;
  return __uint_as_float(x);
}

#define GLDS16(g, l) __builtin_amdgcn_global_load_lds( \
    (const __attribute__((address_space(1))) unsigned int*)(g), \
    (__attribute__((address_space(3))) unsigned int*)(l), 16, 0, 0)

// ---------- row stats + derive fused; optional fused nnz-list extraction ----------
__global__ __launch_bounds__(256) void rowstats_k(const float* __restrict__ A,
                                                  ushort_t* __restrict__ klist,
                                                  int* __restrict__ kcnt,
                                                  float* __restrict__ diag,
                                                  float* __restrict__ dgcn,
                                                  float* __restrict__ dnorm,
                                                  float* __restrict__ rz, int R) {
  int gw = (blockIdx.x * 256 + threadIdx.x) >> 6;
  int lane = threadIdx.x & 63;
  int b = gw / R, i = gw - b * R;
  const float4* row = (const float4*)(A + (long long)gw * R);
  int R4 = R >> 2;
  float s = 0.f;
  ushort_t* lst = klist ? (klist + (long long)gw * LMAX) : (ushort_t*)0;
  int base = 0;
  for (int j = lane; j < R4; j += 64) {
    float4 v = row[j];
    s += v.x + v.y + v.z + v.w;
    if (klist) {
      int c0 = (v.x != 0.f), c1 = (v.y != 0.f), c2 = (v.z != 0.f), c3 = (v.w != 0.f);
      int c = c0 + c1 + c2 + c3;
      int pref = c;
#pragma unroll
      for (int off = 1; off < 64; off <<= 1) {
        int t = __shfl_up(pref, off);
        if (lane >= off) pref += t;
      }
      int tot = __shfl(pref, 63);
      int p = base + pref - c;
      int col = j * 4;
      if (c0) { if (p < LMAX) lst[p] = (ushort_t)col;       p++; }
      if (c1) { if (p < LMAX) lst[p] = (ushort_t)(col + 1); p++; }
      if (c2) { if (p < LMAX) lst[p] = (ushort_t)(col + 2); p++; }
      if (c3) { if (p < LMAX) lst[p] = (ushort_t)(col + 3); p++; }
      base += tot;
    }
  }
  for (int off = 32; off > 0; off >>= 1) s += __shfl_down(s, off);
  if (lane == 0) {
    float dg = A[(long long)gw * R + i];
    diag[gw] = dg;
    dgcn[gw]  = rsqrtf(fmaxf(s - dg + 1.f, 1.f));
    dnorm[gw] = rsqrtf(fmaxf(s + 1.f, 1.f));
    rz[gw]    = s > 0.f ? 1.f : 0.f;
    if (kcnt) kcnt[gw] = base < LMAX ? base : LMAX;
  }
}

// ---------- L1: rowstats + wvec fused (dnorm consumed in-register) ----------
__global__ __launch_bounds__(256) void rowstatsw_k(const float* __restrict__ A,
                                                   const float* __restrict__ X,
                                                   const float* __restrict__ Watt,
                                                   const float* __restrict__ batt,
                                                   float* __restrict__ dnorm,
                                                   float* __restrict__ rz,
                                                   float* __restrict__ w, int R) {
  int gw = (blockIdx.x * 256 + threadIdx.x) >> 6;
  int lane = threadIdx.x & 63;
  int b = gw / R;
  const float4* row = (const float4*)(A + (long long)gw * R);
  int R4 = R >> 2;
  float s = 0.f;
  for (int j = lane; j < R4; j += 64) {
    float4 v = row[j];
    s += v.x + v.y + v.z + v.w;
  }
  for (int off = 32; off > 0; off >>= 1) s += __shfl_xor(s, off);
  float dn = rsqrtf(fmaxf(s + 1.f, 1.f));
  const float* xr = X + (long long)gw * HH;
  float t = xr[lane] * Watt[lane] + xr[lane + 64] * Watt[lane + 64];
  for (int off = 32; off > 0; off >>= 1) t += __shfl_down(t, off);
  if (lane == 0) {
    dnorm[gw] = dn;
    rz[gw]    = s > 0.f ? 1.f : 0.f;
    w[gw] = dn * (t + batt[0]);
  }
}

// ---------- fused GCN1: sparse acc + epilogue (relu/mask) + wvec reduce ----------
__global__ __launch_bounds__(256) void spmm1e_k(const ushort_t* __restrict__ klist,
                                                const int* __restrict__ kcnt,
                                                const float* __restrict__ dgcn,
                                                const float* __restrict__ diag,
                                                const float* __restrict__ b1,
                                                const float* __restrict__ mask,
                                                const float* __restrict__ Watt,
                                                const float* __restrict__ batt,
                                                const float* __restrict__ dnorm,
                                                const float* __restrict__ xw,
                                                float* __restrict__ xa,
                                                float* __restrict__ w) {
  int bid = blockIdx.x;
  int sw = (bid & 7) * ((int)gridDim.x >> 3) + (bid >> 3);
  int gw = (sw * 256 + threadIdx.x) >> 6;
  int lane = threadIdx.x & 63;
  int b = gw >> 11;
  int cnt = kcnt[gw];
  const ushort_t* kl = klist + (long long)gw * LMAX;
  int myk = (lane < cnt) ? (int)kl[lane] : 0;
  float myd = dgcn[b * NN + myk];
  float s0 = 0.f, s1 = 0.f;
  for (int t = 0; t < cnt; t++) {
    int k = __shfl(myk, t);
    float d = __shfl(myd, t);
    const float* xr = xw + ((long long)b * NN + k) * HH;
    s0 += d * xr[lane];
    s1 += d * xr[lane + 64];
  }
  long long o = (long long)gw * HH;
  float d = dgcn[gw];
  float dgv = diag[gw];
  float mv = mask[gw];
  float xw0 = xw[o + lane], xw1v = xw[o + lane + 64];
  float t0 = d * (s0 + (1.f - dgv) * d * xw0) + b1[lane];
  float t1 = d * (s1 + (1.f - dgv) * d * xw1v) + b1[lane + 64];
  t0 *= mv; t1 *= mv;
  float x0 = fmaxf(t0, 0.f), x1 = fmaxf(t1, 0.f);
  xa[o + lane] = x0;
  xa[o + lane + 64] = x1;
  float t = x0 * Watt[lane] + x1 * Watt[lane + 64];
  for (int off = 32; off > 0; off >>= 1) t += __shfl_down(t, off);
  if (lane == 0) w[gw] = dnorm[gw] * (t + batt[0]);
}

// ---------- sparse G3n: x2c[m][f] = cw_m * sum_{k in klistC(m)} scale[k] * x1[b][k][f] ----------
__global__ __launch_bounds__(256) void spmm2_k(const ushort_t* __restrict__ klistC,
                                               const int* __restrict__ kcntC,
                                               const float* __restrict__ scalev,
                                               const float* __restrict__ cwk,
                                               const float* __restrict__ xa,
                                               float* __restrict__ x2c) {
  int bid = blockIdx.x;
  int sw = (bid & 7) * ((int)gridDim.x >> 3) + (bid >> 3);
  int gw = (sw * 256 + threadIdx.x) >> 6;   // 0..MC-1
  int lane = threadIdx.x & 63;
  int b = gw / MPAD;
  int cnt = kcntC[gw];
  const ushort_t* kl = klistC + (long long)gw * LP;
  int c64 = cnt < 64 ? cnt : 64;
  int myk = (lane < c64) ? (int)kl[lane] : 0;
  float myc = scalev[b * NN + myk];
  float s0 = 0.f, s1 = 0.f;
  for (int t = 0; t < c64; t++) {
    int k = __shfl(myk, t);
    float c = __shfl(myc, t);
    const float* xr = xa + ((long long)b * NN + k) * HH;
    s0 += c * xr[lane];
    s1 += c * xr[lane + 64];
  }
  if (cnt > 64) {
    int k = kl[64];
    float c = scalev[b * NN + k];
    const float* xr = xa + ((long long)b * NN + k) * HH;
    s0 += c * xr[lane];
    s1 += c * xr[lane + 64];
  }
  float cw = cwk[gw];
  long long o = (long long)gw * HH;
  x2c[o + lane] = cw * s0;
  x2c[o + lane + 64] = cw * s1;
}

// ---------- L0 alpha via nnz gather ----------
__global__ __launch_bounds__(256) void alphaL_k(const ushort_t* __restrict__ klist,
                                                const int* __restrict__ kcnt,
                                                const float* __restrict__ w,
                                                const float* __restrict__ dnorm,
                                                const float* __restrict__ rz,
                                                float* __restrict__ alpha) {
  int gw = (blockIdx.x * 256 + threadIdx.x) >> 6;
  int lane = threadIdx.x & 63;
  int b = gw >> 11, i = gw & (NN - 1);
  int cnt = kcnt[gw];
  float s = 0.f;
  if (lane < cnt) s = w[(long long)b * NN + klist[(long long)gw * LMAX + lane]];
  for (int off = 32; off > 0; off >>= 1) s += __shfl_down(s, off);
  if (lane == 0) {
    float aa = rz[gw] * dnorm[gw] * (s + w[(long long)b * NN + i]);
    aa = aa * aa;
    alpha[(long long)b * NN + i] = 1.f / (1.f + expf(-aa));
  }
}

// ---------- L1 alpha (fp32 A) ----------
__global__ __launch_bounds__(256) void alpha_k(const float* __restrict__ A,
                                               const float* __restrict__ w,
                                               const float* __restrict__ dnorm,
                                               const float* __restrict__ rz,
                                               float* __restrict__ alpha, int R) {
  int gw = (blockIdx.x * 256 + threadIdx.x) >> 6;
  int lane = threadIdx.x & 63;
  int b = gw / R, i = gw - b * R;
  const float4* row = (const float4*)(A + (long long)gw * R);
  const float4* wb4 = (const float4*)(w + (long long)b * R);
  int R4 = R >> 2;
  float s = 0.f;
  for (int j = lane; j < R4; j += 64) {
    float4 a = row[j], ww = wb4[j];
    s += a.x * ww.x + a.y * ww.y + a.z * ww.z + a.w * ww.w;
  }
  for (int off = 32; off > 0; off >>= 1) s += __shfl_down(s, off);
  if (lane == 0) {
    float aa = rz[gw] * dnorm[gw] * (s + w[(long long)b * R + i]);
    aa = aa * aa;
    alpha[(long long)b * NN + i] = 1.f / (1.f + expf(-aa));
  }
}

// ---------- exact k-th largest via 4-round radix select ----------
__global__ __launch_bounds__(1024) void topkeep_k(const float* __restrict__ alpha,
                                                  const float* __restrict__ dnorm,
                                                  const float* __restrict__ rz,
                                                  float* __restrict__ colw,
                                                  int* __restrict__ keepidx) {
  __shared__ unsigned vals[NN];
  __shared__ int hist[256];
  __shared__ int wsum[32];
  __shared__ unsigned selp_s;
  __shared__ int selr_s;
  int b = blockIdx.x, t = threadIdx.x;
  vals[t] = __float_as_uint(alpha[b * NN + t]);
  vals[t + 1024] = __float_as_uint(alpha[b * NN + t + 1024]);
  if (t == 0) { selp_s = 0u; selr_s = KSEL; }
  __syncthreads();
  for (int shift = 24; shift >= 0; shift -= 8) {
    if (t < 256) hist[t] = 0;
    __syncthreads();
    unsigned pre = selp_s; int rank = selr_s;
    unsigned hm = (shift == 24) ? 0u : (0xFFFFFFFFu << (shift + 8));
    for (int e = t; e < NN; e += 1024) {
      unsigned v = vals[e];
      if ((v & hm) == (pre & hm)) atomicAdd(&hist[(v >> shift) & 255], 1);
    }
    __syncthreads();
    for (int off2 = 1; off2 < 256; off2 <<= 1) {
      int v = 0;
      if (t < 256 - off2) v = hist[t + off2];
      __syncthreads();
      if (t < 256 - off2) hist[t] += v;
      __syncthreads();
    }
    if (t < 256) {
      int cge = hist[t];
      int cgt = (t == 255) ? 0 : hist[t + 1];
      if (cge >= rank && cgt < rank) {
        selp_s = pre | ((unsigned)t << shift);
        selr_s = rank - cgt;
      }
    }
    __syncthreads();
  }
  float cu = __uint_as_float(selp_s);
  float a0 = __uint_as_float(vals[t]);
  float a1 = __uint_as_float(vals[t + 1024]);
  float c0 = dnorm[b * NN + t]        * fmaxf(a0 + 1e-7f - cu, 0.f);
  float c1 = dnorm[b * NN + t + 1024] * fmaxf(a1 + 1e-7f - cu, 0.f);
  colw[b * NN + t] = c0;
  colw[b * NN + t + 1024] = c1;
  int f0 = (c0 != 0.f && rz[b * NN + t]        != 0.f) ? 1 : 0;
  int f1 = (c1 != 0.f && rz[b * NN + t + 1024] != 0.f) ? 1 : 0;
  int lane = t & 63, wid = t >> 6;
  unsigned long long m0 = __ballot(f0);
  unsigned long long m1 = __ballot(f1);
  if (lane == 0) { wsum[wid] = __popcll(m0); wsum[16 + wid] = __popcll(m1); }
  __syncthreads();
  if (t == 0) { int run = 0; for (int i2 = 0; i2 < 32; i2++) { int v = wsum[i2]; wsum[i2] = run; run += v; } }
  __syncthreads();
  unsigned long long lm = (1ull << lane) - 1ull;
  int p0 = wsum[wid] + __popcll(m0 & lm);
  int p1 = wsum[16 + wid] + __popcll(m1 & lm);
  if (t < MPAD) keepidx[b * MPAD + t] = -1;
  if (t + 1024 < MPAD) keepidx[b * MPAD + t + 1024] = -1;
  __syncthreads();
  if (f0 && p0 < MPAD) keepidx[b * MPAD + p0] = t;
  if (f1 && p1 < MPAD) keepidx[b * MPAD + p1] = t + 1024;
}

// L1 variant: radix select + compact colw only; pad region (>=MPAD) synthesized as 0.5f
__global__ __launch_bounds__(1024) void topcolw_k(const float* __restrict__ alpha,
                                                  const float* __restrict__ dnorm,
                                                  float* __restrict__ colw) {
  __shared__ unsigned vals[NN];
  __shared__ int hist[256];
  __shared__ unsigned selp_s;
  __shared__ int selr_s;
  int b = blockIdx.x, t = threadIdx.x;
  vals[t] = __float_as_uint(alpha[b * NN + t]);            // t < 1024 < MPAD: always real
  vals[t + 1024] = (t + 1024 >= MPAD) ? __float_as_uint(0.5f)
                                      : __float_as_uint(alpha[b * NN + t + 1024]);
  if (t == 0) { selp_s = 0u; selr_s = KSEL; }
  __syncthreads();
  for (int shift = 24; shift >= 0; shift -= 8) {
    if (t < 256) hist[t] = 0;
    __syncthreads();
    unsigned pre = selp_s; int rank = selr_s;
    unsigned hm = (shift == 24) ? 0u : (0xFFFFFFFFu << (shift + 8));
    for (int e = t; e < NN; e += 1024) {
      unsigned v = vals[e];
      if ((v & hm) == (pre & hm)) atomicAdd(&hist[(v >> shift) & 255], 1);
    }
    __syncthreads();
    for (int off2 = 1; off2 < 256; off2 <<= 1) {
      int v = 0;
      if (t < 256 - off2) v = hist[t + off2];
      __syncthreads();
      if (t < 256 - off2) hist[t] += v;
      __syncthreads();
    }
    if (t < 256) {
      int cge = hist[t];
      int cgt = (t == 255) ? 0 : hist[t + 1];
      if (cge >= rank && cgt < rank) {
        selp_s = pre | ((unsigned)t << shift);
        selr_s = rank - cgt;
      }
    }
    __syncthreads();
  }
  float cu = __uint_as_float(selp_s);
  for (int ii = t; ii < MPAD; ii += 1024) {
    float c = fmaxf(__uint_as_float(vals[ii]) + 1e-7f - cu, 0.f);
    colw[b * MPAD + ii] = dnorm[b * MPAD + ii] * c;
  }
}

// ---------- L0 scale via nnz gather ----------
__global__ __launch_bounds__(256) void scaleL_k(const ushort_t* __restrict__ klist,
                                                const int* __restrict__ kcnt,
                                                const float* __restrict__ colw,
                                                const float* __restrict__ dnorm,
                                                const float* __restrict__ rz,
                                                float* __restrict__ scale) {
  int gw = (blockIdx.x * 256 + threadIdx.x) >> 6;
  int lane = threadIdx.x & 63;
  int b = gw >> 11, i = gw & (NN - 1);
  int cnt = kcnt[gw];
  float s = 0.f;
  if (lane < cnt) s = colw[(long long)b * NN + klist[(long long)gw * LMAX + lane]];
  for (int off = 32; off > 0; off >>= 1) s += __shfl_down(s, off);
  if (lane == 0) {
    float rsum = rz[gw] * dnorm[gw] * (s + colw[(long long)b * NN + i]);
    scale[gw] = rz[gw] * dnorm[gw] / fmaxf(rsum, 1e-12f);
  }
}

// ---------- L1 scale (fp32 A) ----------
__global__ __launch_bounds__(256) void scale_k(const float* __restrict__ A,
                                               const float* __restrict__ colw,
                                               const float* __restrict__ dnorm,
                                               const float* __restrict__ rz,
                                               float* __restrict__ scale, int R) {
  int gw = (blockIdx.x * 256 + threadIdx.x) >> 6;
  int lane = threadIdx.x & 63;
  int b = gw / R, i = gw - b * R;
  const float4* row = (const float4*)(A + (long long)gw * R);
  const float4* cw4 = (const float4*)(colw + (long long)b * R);
  int R4 = R >> 2;
  float s = 0.f;
  for (int j = lane; j < R4; j += 64) {
    float4 a = row[j], c = cw4[j];
    s += a.x * c.x + a.y * c.y + a.z * c.z + a.w * c.w;
  }
  for (int off = 32; off > 0; off >>= 1) s += __shfl_down(s, off);
  if (lane == 0) {
    float rsum = rz[gw] * dnorm[gw] * (s + colw[(long long)b * R + i]);
    scale[gw] = rz[gw] * dnorm[gw] / fmaxf(rsum, 1e-12f);
  }
}

// ---------- pack per-(b,j) gather programs + cwk ----------
__global__ __launch_bounds__(256) void packlist_k(const ushort_t* __restrict__ klist,
                                                  const int* __restrict__ kcnt,
                                                  const int* __restrict__ keepidx,
                                                  const float* __restrict__ colw,
                                                  ushort_t* __restrict__ klistC,
                                                  int* __restrict__ kcntC,
                                                  float* __restrict__ cwk) {
  int g = blockIdx.x * 256 + threadIdx.x;   // 0..MC-1
  int b = g / MPAD;
  int rj = keepidx[g];
  ushort_t* dst = klistC + (long long)g * LP;
  int cnt = 0;
  if (rj >= 0) {
    long long gr = (long long)b * NN + rj;
    int c = kcnt[gr];
    const ushort_t* src = klist + gr * LMAX;
    for (int t = 0; t < c; t++) dst[t] = src[t];
    dst[c] = (ushort_t)rj;
    cnt = c + 1;
  }
  kcntC[g] = cnt;
  cwk[g] = (rj >= 0) ? colw[b * NN + rj] : 0.f;
  int pad = (cnt + 7) & ~7;
  for (int t = cnt; t < pad; t++) dst[t] = (ushort_t)ZIDX;
}

// ---------- fused sparse R + A2c (scatter, scale, gather; float2-paired planes) ----------
__global__ __launch_bounds__(256) void sparseA2f_k(const ushort_t* __restrict__ klist,
                                                   const int* __restrict__ kcnt,
                                                   const int* __restrict__ keepidx,
                                                   const float* __restrict__ scalev,
                                                   const ushort_t* __restrict__ klistC,
                                                   const int* __restrict__ kcntC,
                                                   const float* __restrict__ cwk,
                                                   float* __restrict__ A2cF,
                                                   ushort_t* __restrict__ A2cH,
                                                   ushort_t* __restrict__ A2cL) {
  __shared__ float Rs[3 * RSTRIDE * 2];   // 3 planes x RSTRIDE float2 = 49,248 B
  int i0 = blockIdx.x * MI;               // MPAD%MI==0 -> no batch straddle
  int b = i0 / MPAD, im0 = i0 - b * MPAD;
  int tid = threadIdx.x;
  int wid = tid >> 6, lane = tid & 63;
  const float* sb = scalev + (long long)b * NN;

  float4 z4 = make_float4(0.f, 0.f, 0.f, 0.f);
  for (int n = tid * 4; n < 3 * RSTRIDE * 2; n += 1024) *(float4*)&Rs[n] = z4;
  __syncthreads();

  for (int rr = wid; rr < MI; rr += 4) {
    int r = keepidx[i0 + rr];
    if (r < 0) continue;
    int p = rr >> 1, q = rr & 1;
    float* plane = Rs + p * RSTRIDE * 2;
    long long gr = (long long)b * NN + r;
    int cr = kcnt[gr];
    int myk = (lane < cr) ? (int)klist[gr * LMAX + lane] : r;
    float mycoef = sb[myk];
    int mycnt = kcnt[(long long)b * NN + myk];
    for (int i = 0; i < cr; i++) {
      int k = __shfl(myk, i);
      float coef = __shfl(mycoef, i);
      int ck = __shfl(mycnt, i);
      if (lane < ck) {
        int n = (int)klist[((long long)b * NN + k) * LMAX + lane];
        plane[n * 2 + q] += coef;
      }
    }
    float coef = sb[r];
    if (lane < cr) plane[myk * 2 + q] += coef;
  }
  __syncthreads();

  for (int c = tid; c < NN; c += 256) {
    float sc = sb[c];
#pragma unroll
    for (int p = 0; p < 3; p++) {
      float2* e = (float2*)&Rs[(p * RSTRIDE + c) * 2];
      float2 v = *e; v.x *= sc; v.y *= sc; *e = v;
    }
  }
  __syncthreads();

  float cwi[MI];
#pragma unroll
  for (int r = 0; r < MI; r++) cwi[r] = cwk[i0 + r];
  long long ob = (long long)b * MPAD * MPAD + (long long)im0 * MPAD;
  for (int j = tid; j < MPAD; j += 256) {
    int cnt = kcntC[b * MPAD + j];
    const ushort_t* kl = klistC + (long long)(b * MPAD + j) * LP;
    float sx0 = 0.f, sy0 = 0.f, sx1 = 0.f, sy1 = 0.f, sx2 = 0.f, sy2 = 0.f;
    int rounds = (cnt + 7) >> 3;
    for (int t0 = 0; t0 < rounds; t0++) {
      uint4 kv = *(const uint4*)(kl + t0 * 8);
      const ushort_t* kp = (const ushort_t*)&kv;
#pragma unroll
      for (int t = 0; t < 8; t++) {
        int c = kp[t];
        float2 v0 = *(const float2*)&Rs[(0 * RSTRIDE + c) * 2];
        float2 v1 = *(const float2*)&Rs[(1 * RSTRIDE + c) * 2];
        float2 v2 = *(const float2*)&Rs[(2 * RSTRIDE + c) * 2];
        sx0 += v0.x; sy0 += v0.y;
        sx1 += v1.x; sy1 += v1.y;
        sx2 += v2.x; sy2 += v2.y;
      }
    }
    float sv[MI] = {sx0, sy0, sx1, sy1, sx2, sy2};
    float cwj = cwk[b * MPAD + j];
#pragma unroll
    for (int r = 0; r < MI; r++) {
      float vq = floorf(cwi[r] * cwj * sv[r] * 10000.f) / 10000.f;
      ushort_t h = f2bf(vq);
      long long o = ob + (long long)r * MPAD + j;
      A2cF[o] = vq;
      A2cH[o] = h;
      A2cL[o] = f2bf(vq - bf2f(h));
    }
  }
}

// ---------- L1 compact S2^T ----------
__global__ void writeS2c_k(const float* __restrict__ A2c, const float* __restrict__ scale,
                           const float* __restrict__ colw,
                           ushort_t* __restrict__ Sh, ushort_t* __restrict__ Sl) {
  int g = blockIdx.x * 256 + threadIdx.x;
  int bl = g / (MPAD / 4);
  int k = (g - bl * (MPAD / 4)) * 4;
  int b = bl / MPAD, l = bl - b * MPAD;
  long long o = (long long)bl * MPAD + k;
  float cw = colw[b * MPAD + l];
  float4 sc = *(const float4*)(scale + b * MPAD + k);
  float4 av = *(const float4*)(A2c + o);
  float v0 = sc.x * (av.x + (float)(k     == l)) * cw;
  float v1 = sc.y * (av.y + (float)(k + 1 == l)) * cw;
  float v2 = sc.z * (av.z + (float)(k + 2 == l)) * cw;
  float v3 = sc.w * (av.w + (float)(k + 3 == l)) * cw;
  ushort_t h0 = f2bf(v0), h1 = f2bf(v1), h2 = f2bf(v2), h3 = f2bf(v3);
  *(uint2*)&Sh[o] = make_uint2((unsigned)h0 | ((unsigned)h1 << 16),
                               (unsigned)h2 | ((unsigned)h3 << 16));
  ushort_t l0 = f2bf(v0 - bf2f(h0)), l1 = f2bf(v1 - bf2f(h1));
  ushort_t l2 = f2bf(v2 - bf2f(h2)), l3 = f2bf(v3 - bf2f(h3));
  *(uint2*)&Sl[o] = make_uint2((unsigned)l0 | ((unsigned)l1 << 16),
                               (unsigned)l2 | ((unsigned)l3 << 16));
}

// ============ MFMA split-bf16 GEMM, batch->XCD swizzled; optional symmetric-output mode ============
// SYMM: output known symmetric -> enumerate lower-triangle tiles (tn <= 2*tm+1 at BM=128,BN=64),
//       mirror-write strictly-lower tiles (tn < 2*tm). EPI==6 writes quantized fp32.
template<int SA, int SB, int EPI, int BN, int SYMM>
__global__ __launch_bounds__(256) void mgemm_k(
    const ushort_t* __restrict__ Ah, const ushort_t* __restrict__ Al,
    const ushort_t* __restrict__ Bh, const ushort_t* __restrict__ Bl,
    float* __restrict__ Co, ushort_t* __restrict__ Toh, ushort_t* __restrict__ Tol,
    int M, int Ncol, int K, long long sA, long long sB, long long sC,
    int gx, int ks, long long sPart) {
  constexpr int NJ = BN / 32;            // j-fragments per wave (2 or 4)
  __shared__ ushort_t Ahs[128 * 32];
  __shared__ ushort_t Bhs[BN * 32];
  __shared__ ushort_t Als[SA ? 128 * 32 : 64];
  __shared__ ushort_t Bls[SB ? BN * 32 : 64];

  int tid = threadIdx.x;
  int id = blockIdx.x;
  long long bz = id & 7;
  int rest = id >> 3;
  int kslice = rest % ks;
  int t0 = rest / ks;
  int tm, tn;
  if constexpr (SYMM) {
    tm = 0;
    while ((tm + 1) * (tm + 2) <= t0) tm++;   // base(tm)=tm*(tm+1); row width 2tm+2
    tn = t0 - tm * (tm + 1);
  } else {
    tn = t0 % gx; tm = t0 / gx;
  }
  int n0 = tn * BN, m0 = tm * 128;
  const ushort_t* Ahb = Ah + bz * sA;
  const ushort_t* Alb = SA ? (Al + bz * sA) : Ah;
  const ushort_t* Bhb = Bh + bz * sB;
  const ushort_t* Blb = SB ? (Bl + bz * sB) : Bh;

  int sr = tid >> 2;
  int sc = (tid & 3) * 8;
  int lane = tid & 63, w = tid >> 6;
  int wm = (w >> 1) * 64, wn = (w & 1) * (BN / 2);
  int fr = lane & 15;
  int fo = (lane >> 4) * 8;
  int q = lane >> 4;

  f32x4 acc[4][NJ];
  f32x4 zz = {0.f, 0.f, 0.f, 0.f};
#pragma unroll
  for (int i = 0; i < 4; i++)
#pragma unroll
    for (int j = 0; j < NJ; j++) acc[i][j] = zz;

  int Kpc = K / ks;
  int kbeg = kslice * Kpc;
  for (int k0 = kbeg; k0 < kbeg + Kpc; k0 += 32) {
    __syncthreads();
#pragma unroll
    for (int r = 0; r < 128; r += 64) {
      GLDS16(Ahb + (long long)(m0 + sr + r) * K + k0 + sc, &Ahs[(r + sr) * 32 + sc]);
      if constexpr (SA) {
        GLDS16(Alb + (long long)(m0 + sr + r) * K + k0 + sc, &Als[(r + sr) * 32 + sc]);
      }
    }
#pragma unroll
    for (int r = 0; r < BN; r += 64) {
      GLDS16(Bhb + (long long)(n0 + sr + r) * K + k0 + sc, &Bhs[(r + sr) * 32 + sc]);
      if constexpr (SB) {
        GLDS16(Blb + (long long)(n0 + sr + r) * K + k0 + sc, &Bls[(r + sr) * 32 + sc]);
      }
    }
    __syncthreads();

    short8 ah[4], al[4], bh[NJ], bl[NJ];
#pragma unroll
    for (int i = 0; i < 4; i++) {
      ah[i] = *(const short8*)&Ahs[(wm + i * 16 + fr) * 32 + fo];
      if constexpr (SA) al[i] = *(const short8*)&Als[(wm + i * 16 + fr) * 32 + fo];
    }
#pragma unroll
    for (int j = 0; j < NJ; j++) {
      bh[j] = *(const short8*)&Bhs[(wn + j * 16 + fr) * 32 + fo];
      if constexpr (SB) bl[j] = *(const short8*)&Bls[(wn + j * 16 + fr) * 32 + fo];
    }
#pragma unroll
    for (int i = 0; i < 4; i++)
#pragma unroll
      for (int j = 0; j < NJ; j++) {
        acc[i][j] = __builtin_amdgcn_mfma_f32_16x16x32_bf16(ah[i], bh[j], acc[i][j], 0, 0, 0);
        if constexpr (SB)
          acc[i][j] = __builtin_amdgcn_mfma_f32_16x16x32_bf16(ah[i], bl[j], acc[i][j], 0, 0, 0);
        if constexpr (SA)
          acc[i][j] = __builtin_amdgcn_mfma_f32_16x16x32_bf16(al[i], bh[j], acc[i][j], 0, 0, 0);
      }
  }

#pragma unroll
  for (int i = 0; i < 4; i++)
#pragma unroll
    for (int j = 0; j < NJ; j++)
#pragma unroll
      for (int r = 0; r < 4; r++) {
        float v = acc[i][j][r];
        int row = m0 + wm + i * 16 + q * 4 + r;
        int col = n0 + wn + j * 16 + fr;
        long long idx = bz * sC + (long long)row * Ncol + col;
        if constexpr (EPI == 0) {
          Co[kslice * sPart + idx] = v;
        } else if constexpr (EPI == 1) {
          ushort_t h = f2bf(v);
          Toh[idx] = h;
          Tol[idx] = f2bf(v - bf2f(h));
        } else {  // EPI == 6: quantized fp32 (+ mirror when SYMM strictly-lower tile)
          float vq = floorf(v * 10000.f) / 10000.f;
          Co[idx] = vq;
          if constexpr (SYMM) {
            if (tn < 2 * tm) Co[bz * sC + (long long)col * Ncol + row] = vq;
          }
        }
      }
}

// ---------- final-GCN mean weights: w_l = d_l*(cs_l - d_l*diag_l + d_l), cs = A3 row-dot d ----------
__global__ __launch_bounds__(256) void wfin_k(const float* __restrict__ A3,
                                              const float* __restrict__ dgcn,
                                              const float* __restrict__ diag,
                                              float* __restrict__ wv) {
  int gw = (blockIdx.x * 256 + threadIdx.x) >> 6;   // 0..MC-1
  int lane = threadIdx.x & 63;
  int b = gw / MPAD;
  const float4* row = (const float4*)(A3 + (long long)gw * MPAD);
  const float4* d4 = (const float4*)(dgcn + (long long)b * MPAD);
  float s = 0.f;
  for (int j = lane; j < MPAD / 4; j += 64) {
    float4 a = row[j], d = d4[j];
    s += a.x * d.x + a.y * d.y + a.z * d.z + a.w * d.w;
  }
  for (int off = 32; off > 0; off >>= 1) s += __shfl_down(s, off);
  if (lane == 0) {
    float dl = dgcn[gw];
    wv[gw] = dl * (s - dl * diag[gw] + dl);
  }
}

// ---------- z_k = scale_k*( sum_l A2c[k,l]*colw_l*w_l + colw_k*w_k ) ----------
__global__ __launch_bounds__(256) void zfin_k(const float* __restrict__ A2c,
                                              const float* __restrict__ scalev,
                                              const float* __restrict__ colwv,
                                              const float* __restrict__ wv,
                                              float* __restrict__ zv) {
  int gw = (blockIdx.x * 256 + threadIdx.x) >> 6;   // 0..MC-1
  int lane = threadIdx.x & 63;
  int b = gw / MPAD;
  const float4* row = (const float4*)(A2c + (long long)gw * MPAD);
  const float4* c4 = (const float4*)(colwv + (long long)b * MPAD);
  const float4* w4 = (const float4*)(wv + (long long)b * MPAD);
  float s = 0.f;
  for (int j = lane; j < MPAD / 4; j += 64) {
    float4 a = row[j], c = c4[j], w = w4[j];
    s += a.x * c.x * w.x + a.y * c.y * w.y + a.z * c.z * w.z + a.w * c.w * w.w;
  }
  for (int off = 32; off > 0; off >>= 1) s += __shfl_down(s, off);
  if (lane == 0) {
    zv[gw] = scalev[gw] * (s + colwv[gw] * wv[gw]);
  }
}

// ---------- part[b][c][h] = sum_{r<128} z[b*MPAD+c*128+r] * x2c[...][h] ----------
__global__ void zx_k(const float* __restrict__ zv, const float* __restrict__ x2c,
                     float* __restrict__ part) {
  int b = blockIdx.y, c = blockIdx.x, h = threadIdx.x;   // 128 threads
  const float* p = x2c + ((long long)(b * MPAD + c * 128)) * HH + h;
  const float* zp = zv + b * MPAD + c * 128;
  float s = 0.f;
  for (int r = 0; r < 128; r++) s += zp[r] * p[(long long)r * HH];
  part[(b * 9 + c) * HH + h] = s;
}

// ---------- out2[f] = b2[f] + (1/NN)*sum_h wx3_h*W2[h,f] ----------
__global__ __launch_bounds__(256) void fout2_k(const float* __restrict__ part,
                                               const float* __restrict__ W2,
                                               const float* __restrict__ b2,
                                               float* __restrict__ out) {
  __shared__ float wx3[HH];
  int b = blockIdx.x, f = threadIdx.x;   // 256 threads
  if (f < HH) {
    float s = 0.f;
    for (int c = 0; c < 9; c++) s += part[(b * 9 + c) * HH + f];
    wx3[f] = s;
  }
  __syncthreads();
  float s = 0.f;
  for (int h = 0; h < HH; h++) s += wx3[h] * W2[h * FF + f];
  out[b * (HH + FF) + HH + f] = b2[f] + s * (1.f / NN);
}

// ---------- two-stage column means (GCN1) ----------
__global__ void pmean_k(const float* __restrict__ X, float* __restrict__ part,
                        int Nn, int Fd, int rpc) {
  int b = blockIdx.y, c = blockIdx.x, f = threadIdx.x;
  const float* p = X + ((long long)b * Nn + (long long)c * rpc) * Fd + f;
  float s = 0.f;
  for (int r = 0; r < rpc; r++) s += p[(long long)r * Fd];
  part[((long long)b * gridDim.x + c) * Fd + f] = s;
}

__global__ void fmean_k(const float* __restrict__ part, int nch, int Fd, float corr,
                        const float* __restrict__ bias, float* __restrict__ out, int outoff) {
  int b = blockIdx.x, f = threadIdx.x;
  float s = 0.f;
  for (int c = 0; c < nch; c++) s += part[((long long)b * nch + c) * Fd + f];
  float cv = bias ? corr * bias[f] : 0.f;
  out[b * (HH + FF) + outoff + f] = s * (1.f / NN) + cv;
}

// ---------- fp32 VALU GEMM (GCN1 xw1) ----------
__global__ __launch_bounds__(256) void gemm_k(const float* __restrict__ A, const float* __restrict__ B,
                                              float* __restrict__ C,
                                              int M, int Nw, int Kk,
                                              long long sA, long long sB, long long sC) {
  __shared__ float As[16][128];
  __shared__ float Bs[16][128];
  int tid = threadIdx.x;
  int n0 = blockIdx.x * 128, m0 = blockIdx.y * 128;
  int bz = blockIdx.z;
  const float* Ab = A + (long long)bz * sA;
  const float* Bb = B + (long long)bz * sB;
  float* Cb = C + (long long)bz * sC;
  float acc[8][8];
#pragma unroll
  for (int i = 0; i < 8; i++)
#pragma unroll
    for (int j = 0; j < 8; j++) acc[i][j] = 0.f;
  int tx = tid & 15, ty = tid >> 4;

  for (int k0 = 0; k0 < Kk; k0 += 16) {
    {
      int r = tid >> 2, c = (tid & 3) << 2;
#pragma unroll
      for (int rr = 0; rr < 2; rr++) {
        int rrow = r + rr * 64;
        float4 v = *(const float4*)(Ab + (long long)(m0 + rrow) * Kk + k0 + c);
        As[c + 0][rrow] = v.x; As[c + 1][rrow] = v.y;
        As[c + 2][rrow] = v.z; As[c + 3][rrow] = v.w;
      }
    }
    {
      int kk = tid >> 5, cc = (tid & 31) << 2;
#pragma unroll
      for (int k2 = 0; k2 < 2; k2++) {
        float4 v = *(const float4*)(Bb + (long long)(k0 + kk + k2 * 8) * Nw + n0 + cc);
        *(float4*)&Bs[kk + k2 * 8][cc] = v;
      }
    }
    __syncthreads();
#pragma unroll
    for (int kk = 0; kk < 16; kk++) {
      float a[8], bb[8];
      *(float4*)&a[0]  = *(float4*)&As[kk][ty * 8];
      *(float4*)&a[4]  = *(float4*)&As[kk][ty * 8 + 4];
      *(float4*)&bb[0] = *(float4*)&Bs[kk][tx * 8];
      *(float4*)&bb[4] = *(float4*)&Bs[kk][tx * 8 + 4];
#pragma unroll
      for (int i = 0; i < 8; i++)
#pragma unroll
        for (int j = 0; j < 8; j++) acc[i][j] += a[i] * bb[j];
    }
    __syncthreads();
  }
#pragma unroll
  for (int i = 0; i < 8; i++) {
    float* cp = Cb + (long long)(m0 + ty * 8 + i) * Nw + n0 + tx * 8;
    *(float4*)cp = *(float4*)&acc[i][0];
    *(float4*)(cp + 4) = *(float4*)&acc[i][4];
  }
}

extern "C" void kernel_launch(void* const* d_in, const int* in_sizes, int n_in,
                              void* d_out, int out_size, void* d_ws, size_t ws_size,
                              hipStream_t stream) {
  const float* x    = (const float*)d_in[0];
  const float* adj  = (const float*)d_in[1];
  const float* mask = (const float*)d_in[2];
  const float* W1   = (const float*)d_in[3];
  const float* b1   = (const float*)d_in[4];
  const float* Watt = (const float*)d_in[5];
  const float* batt = (const float*)d_in[6];
  const float* W2   = (const float*)d_in[7];
  const float* b2   = (const float*)d_in[8];
  float* out = (float*)d_out;

  const long long CSTR = (long long)MPAD * NN;
  const long long CTOT = (long long)NB * CSTR;
  const long long M2   = (long long)MPAD * MPAD;
  const long long M2T  = (long long)NB * M2;
  const long long NH   = (long long)NROWS * HH;     // 2,097,152
  const long long MH   = (long long)MC * HH;        // 1,179,648

  // ---- workspace ----
  float* ws = (float*)d_ws;
  long long off = 0;
  ushort_t* S2cH = (ushort_t*)(ws + off); off += M2T;
  float* A2CR = ws + off; off += M2T * 2;
  float* TcF  = ws + off; off += CTOT;
  float* A3F  = ws + off; off += CTOT / 2;   // A3 fp32 (M2T floats; extends into xa, dead by then)
  float* xa   = ws + off; off += NH;
  float* x2c  = ws + off; off += MH;
  float* x3c  = ws + off; off += MH;
  float* diag   = ws + off; off += NROWS;
  float* dgcn   = ws + off; off += NROWS;
  float* dnorm  = ws + off; off += NROWS;
  float* rz     = ws + off; off += NROWS;
  float* wv     = ws + off; off += NROWS;
  float* alphav = ws + off; off += (long long)NB * NN;
  float* colwv  = ws + off; off += NROWS;
  float* scalev = ws + off; off += NROWS;
  off += NROWS / 2;  // (unused)
  off += NROWS / 2;  // (unused)
  int* keepidx  = (int*)(ws + off); off += NB * MPAD;
  float* cwk    = ws + off; off += MC;
  float* partm  = ws + off; off += NB * 16 * FF;

  ushort_t* S2cL = S2cH + M2T;
  float* A2cF = A2CR;
  ushort_t* A2cH = (ushort_t*)(A2CR + M2T);
  ushort_t* A2cL = A2cH + M2T;

  // nnz lists + packed gather programs live in the x3c region
  ushort_t* klist = (ushort_t*)x3c;                  // NROWS*LMAX ushorts
  int* kcnt = (int*)(x3c + (long long)NROWS * (LMAX / 2));
  ushort_t* klistC = (ushort_t*)(x3c + (long long)NROWS * (LMAX / 2) + NROWS);
  int* kcntC = (int*)(x3c + (long long)NROWS * (LMAX / 2) + NROWS + (long long)MC * LP / 2);

  // TcF phase aliases
  float* u1 = TcF;                                   // GCN1 xw1 (NH)
  ushort_t* Tc2H = (ushort_t*)TcF;                   // L1 tmp2 splits (M2T each) [after GCN1]
  ushort_t* Tc2L = Tc2H + M2T;

  // ================= GCN1 (full space, fused sparse acc + epilogue + wvec) =================
  rowstats_k<<<NROWS / 4, 256, 0, stream>>>(adj, klist, kcnt, diag, dgcn, dnorm, rz, NN);
  gemm_k<<<dim3(1, NN / 128, NB), 256, 0, stream>>>(
      x, W1, u1, NN, HH, FF,
      (long long)NN * FF, 0, (long long)NN * HH);
  spmm1e_k<<<NROWS / 4, 256, 0, stream>>>(klist, kcnt, dgcn, diag, b1, mask,
                                          Watt, batt, dnorm, u1, xa, wv);
  pmean_k<<<dim3(16, NB), HH, 0, stream>>>(xa, partm, NN, HH, 128);
  fmean_k<<<NB, HH, 0, stream>>>(partm, 16, HH, 0.f, 0, out, 0);

  // ================= coarsen layer 0 (sparse path) =================
  alphaL_k<<<NROWS / 4, 256, 0, stream>>>(klist, kcnt, wv, dnorm, rz, alphav);
  topkeep_k<<<NB, 1024, 0, stream>>>(alphav, dnorm, rz, colwv, keepidx);
  scaleL_k<<<NROWS / 4, 256, 0, stream>>>(klist, kcnt, colwv, dnorm, rz, scalev);
  packlist_k<<<MC / 256, 256, 0, stream>>>(klist, kcnt, keepidx, colwv, klistC, kcntC, cwk);
  sparseA2f_k<<<MC / MI, 256, 0, stream>>>(klist, kcnt, keepidx, scalev,
                                           klistC, kcntC, cwk, A2cF, A2cH, A2cL);
  spmm2_k<<<MC / 4, 256, 0, stream>>>(klistC, kcntC, scalev, cwk, xa, x2c);

  // ================= coarsen layer 1 (all compact) =================
  rowstatsw_k<<<MC / 4, 256, 0, stream>>>(A2cF, x2c, Watt, batt, dnorm, rz, wv, MPAD);
  alpha_k<<<MC / 4, 256, 0, stream>>>(A2cF, wv, dnorm, rz, alphav, MPAD);
  topcolw_k<<<NB, 1024, 0, stream>>>(alphav, dnorm, colwv);
  scale_k<<<MC / 4, 256, 0, stream>>>(A2cF, colwv, dnorm, rz, scalev, MPAD);
  writeS2c_k<<<(int)(M2T / 4 / 256), 256, 0, stream>>>(A2cF, scalev, colwv, S2cH, S2cL);
  // G1': tmp2^T = S2^T @ A2c, 128x64 tiles (1296 blocks)
  mgemm_k<1, 1, 1, 64, 0><<<(MPAD / 128) * (MPAD / 64) * NB, 256, 0, stream>>>(
      S2cH, S2cL, A2cH, A2cL, 0, Tc2H, Tc2L,
      MPAD, MPAD, MPAD, M2, M2, M2, MPAD / 64, 1, 0);
  // G2': A3 = S2^T @ tmp2 quantized, symmetric: lower-triangle tiles (90x8=720 blocks) + mirror
  mgemm_k<1, 1, 6, 64, 1><<<90 * NB, 256, 0, stream>>>(
      S2cH, S2cL, Tc2H, Tc2L, A3F, 0, 0,
      MPAD, MPAD, MPAD, M2, M2, M2, 0, 1, 0);

  // ================= final GCN mean (fully linear; no GEMMs) =================
  rowstats_k<<<MC / 4, 256, 0, stream>>>(A3F, 0, 0, diag, dgcn, dnorm, rz, MPAD);
  wfin_k<<<MC / 4, 256, 0, stream>>>(A3F, dgcn, diag, wv);
  zfin_k<<<MC / 4, 256, 0, stream>>>(A2cF, scalev, colwv, wv, alphav /*zv*/);
  zx_k<<<dim3(9, NB), HH, 0, stream>>>(alphav, x2c, partm);
  fout2_k<<<NB, FF, 0, stream>>>(partm, W2, b2, out);
}

// Round 13
// 654.416 us; speedup vs baseline: 1.7413x; 1.0099x over previous
//
#include <hip/hip_runtime.h>
#include <math.h>

#define NN 2048
#define NB 8
#define FF 256
#define HH 128
#define KSEL 1025
#define NROWS (NB*NN)
#define MPAD 1152
#define MC (MPAD*NB)
#define LMAX 64
// sparseA2 tiling
#define MI 6
#define RSTRIDE 2052
#define ZIDX 2048
#define LP 72

typedef unsigned short ushort_t;
typedef __attribute__((ext_vector_type(8))) short short8;
typedef __attribute__((ext_vector_type(4))) float f32x4;

__device__ inline ushort_t f2bf(float f) {
  unsigned u = __float_as_uint(f);
  unsigned r = (u + 0x7FFFu + ((u >> 16) & 1u)) >> 16;
  return (ushort_t)r;
}
__device__ inline float bf2f(ushort_t u) {
  unsigned x = ((unsigned)u) << 16;
  return __uint_as_float(x);
}

#define GLDS16(g, l) __builtin_amdgcn_global_load_lds( \
    (const __attribute__((address_space(1))) unsigned int*)(g), \
    (__attribute__((address_space(3))) unsigned int*)(l), 16, 0, 0)

// ---------- row stats + derive fused; optional fused nnz-list extraction ----------
// list positions assigned lane-major (lane l covers cols 4l..4l+3) via ballot prefix.
__global__ __launch_bounds__(256) void rowstats_k(const float* __restrict__ A,
                                                  ushort_t* __restrict__ klist,
                                                  int* __restrict__ kcnt,
                                                  float* __restrict__ diag,
                                                  float* __restrict__ dgcn,
                                                  float* __restrict__ dnorm,
                                                  float* __restrict__ rz, int R) {
  int gw = (blockIdx.x * 256 + threadIdx.x) >> 6;
  int lane = threadIdx.x & 63;
  int b = gw / R, i = gw - b * R;
  const float4* row = (const float4*)(A + (long long)gw * R);
  int R4 = R >> 2;
  float s = 0.f;
  ushort_t* lst = klist ? (klist + (long long)gw * LMAX) : (ushort_t*)0;
  int base = 0;
  unsigned long long lm = (1ull << lane) - 1ull;
  for (int j = lane; j < R4; j += 64) {
    float4 v = row[j];
    s += v.x + v.y + v.z + v.w;
    if (klist) {
      int c0 = (v.x != 0.f), c1 = (v.y != 0.f), c2 = (v.z != 0.f), c3 = (v.w != 0.f);
      unsigned long long m0 = __ballot(c0), m1 = __ballot(c1);
      unsigned long long m2 = __ballot(c2), m3 = __ballot(c3);
      int pre = __popcll(m0 & lm) + __popcll(m1 & lm) + __popcll(m2 & lm) + __popcll(m3 & lm);
      int tot = __popcll(m0) + __popcll(m1) + __popcll(m2) + __popcll(m3);
      int p = base + pre;
      int col = j * 4;
      if (c0) { if (p < LMAX) lst[p] = (ushort_t)col;       p++; }
      if (c1) { if (p < LMAX) lst[p] = (ushort_t)(col + 1); p++; }
      if (c2) { if (p < LMAX) lst[p] = (ushort_t)(col + 2); p++; }
      if (c3) { if (p < LMAX) lst[p] = (ushort_t)(col + 3); p++; }
      base += tot;
    }
  }
  for (int off = 32; off > 0; off >>= 1) s += __shfl_down(s, off);
  if (lane == 0) {
    float dg = A[(long long)gw * R + i];
    diag[gw] = dg;
    dgcn[gw]  = rsqrtf(fmaxf(s - dg + 1.f, 1.f));
    dnorm[gw] = rsqrtf(fmaxf(s + 1.f, 1.f));
    rz[gw]    = s > 0.f ? 1.f : 0.f;
    if (kcnt) kcnt[gw] = base < LMAX ? base : LMAX;
  }
}

// ---------- L1: rowstats + wvec fused (dnorm consumed in-register) ----------
__global__ __launch_bounds__(256) void rowstatsw_k(const float* __restrict__ A,
                                                   const float* __restrict__ X,
                                                   const float* __restrict__ Watt,
                                                   const float* __restrict__ batt,
                                                   float* __restrict__ dnorm,
                                                   float* __restrict__ rz,
                                                   float* __restrict__ w, int R) {
  int gw = (blockIdx.x * 256 + threadIdx.x) >> 6;
  int lane = threadIdx.x & 63;
  int b = gw / R;
  const float4* row = (const float4*)(A + (long long)gw * R);
  int R4 = R >> 2;
  float s = 0.f;
  for (int j = lane; j < R4; j += 64) {
    float4 v = row[j];
    s += v.x + v.y + v.z + v.w;
  }
  for (int off = 32; off > 0; off >>= 1) s += __shfl_xor(s, off);
  float dn = rsqrtf(fmaxf(s + 1.f, 1.f));
  const float* xr = X + (long long)gw * HH;
  float t = xr[lane] * Watt[lane] + xr[lane + 64] * Watt[lane + 64];
  for (int off = 32; off > 0; off >>= 1) t += __shfl_down(t, off);
  if (lane == 0) {
    dnorm[gw] = dn;
    rz[gw]    = s > 0.f ? 1.f : 0.f;
    w[gw] = dn * (t + batt[0]);
  }
}

// ---------- fused GCN1: sparse acc + epilogue (relu/mask) + wvec reduce ----------
__global__ __launch_bounds__(256) void spmm1e_k(const ushort_t* __restrict__ klist,
                                                const int* __restrict__ kcnt,
                                                const float* __restrict__ dgcn,
                                                const float* __restrict__ diag,
                                                const float* __restrict__ b1,
                                                const float* __restrict__ mask,
                                                const float* __restrict__ Watt,
                                                const float* __restrict__ batt,
                                                const float* __restrict__ dnorm,
                                                const float* __restrict__ xw,
                                                float* __restrict__ xa,
                                                float* __restrict__ w) {
  int bid = blockIdx.x;
  int sw = (bid & 7) * ((int)gridDim.x >> 3) + (bid >> 3);
  int gw = (sw * 256 + threadIdx.x) >> 6;
  int lane = threadIdx.x & 63;
  int b = gw >> 11;
  int cnt = kcnt[gw];
  const ushort_t* kl = klist + (long long)gw * LMAX;
  int myk = (lane < cnt) ? (int)kl[lane] : 0;
  float myd = dgcn[b * NN + myk];
  float s0 = 0.f, s1 = 0.f;
  for (int t = 0; t < cnt; t++) {
    int k = __shfl(myk, t);
    float d = __shfl(myd, t);
    const float* xr = xw + ((long long)b * NN + k) * HH;
    s0 += d * xr[lane];
    s1 += d * xr[lane + 64];
  }
  long long o = (long long)gw * HH;
  float d = dgcn[gw];
  float dgv = diag[gw];
  float mv = mask[gw];
  float xw0 = xw[o + lane], xw1v = xw[o + lane + 64];
  float t0 = d * (s0 + (1.f - dgv) * d * xw0) + b1[lane];
  float t1 = d * (s1 + (1.f - dgv) * d * xw1v) + b1[lane + 64];
  t0 *= mv; t1 *= mv;
  float x0 = fmaxf(t0, 0.f), x1 = fmaxf(t1, 0.f);
  xa[o + lane] = x0;
  xa[o + lane + 64] = x1;
  float t = x0 * Watt[lane] + x1 * Watt[lane + 64];
  for (int off = 32; off > 0; off >>= 1) t += __shfl_down(t, off);
  if (lane == 0) w[gw] = dnorm[gw] * (t + batt[0]);
}

// ---------- sparse G3n: x2c[m][f] = cw_m * sum_{k in klistC(m)} scale[k] * x1[b][k][f] ----------
__global__ __launch_bounds__(256) void spmm2_k(const ushort_t* __restrict__ klistC,
                                               const int* __restrict__ kcntC,
                                               const float* __restrict__ scalev,
                                               const float* __restrict__ cwk,
                                               const float* __restrict__ xa,
                                               float* __restrict__ x2c) {
  int bid = blockIdx.x;
  int sw = (bid & 7) * ((int)gridDim.x >> 3) + (bid >> 3);
  int gw = (sw * 256 + threadIdx.x) >> 6;   // 0..MC-1
  int lane = threadIdx.x & 63;
  int b = gw / MPAD;
  int cnt = kcntC[gw];
  const ushort_t* kl = klistC + (long long)gw * LP;
  int c64 = cnt < 64 ? cnt : 64;
  int myk = (lane < c64) ? (int)kl[lane] : 0;
  float myc = scalev[b * NN + myk];
  float s0 = 0.f, s1 = 0.f;
  for (int t = 0; t < c64; t++) {
    int k = __shfl(myk, t);
    float c = __shfl(myc, t);
    const float* xr = xa + ((long long)b * NN + k) * HH;
    s0 += c * xr[lane];
    s1 += c * xr[lane + 64];
  }
  if (cnt > 64) {
    int k = kl[64];
    float c = scalev[b * NN + k];
    const float* xr = xa + ((long long)b * NN + k) * HH;
    s0 += c * xr[lane];
    s1 += c * xr[lane + 64];
  }
  float cw = cwk[gw];
  long long o = (long long)gw * HH;
  x2c[o + lane] = cw * s0;
  x2c[o + lane + 64] = cw * s1;
}

// ---------- L0 alpha via nnz gather ----------
__global__ __launch_bounds__(256) void alphaL_k(const ushort_t* __restrict__ klist,
                                                const int* __restrict__ kcnt,
                                                const float* __restrict__ w,
                                                const float* __restrict__ dnorm,
                                                const float* __restrict__ rz,
                                                float* __restrict__ alpha) {
  int gw = (blockIdx.x * 256 + threadIdx.x) >> 6;
  int lane = threadIdx.x & 63;
  int b = gw >> 11, i = gw & (NN - 1);
  int cnt = kcnt[gw];
  float s = 0.f;
  if (lane < cnt) s = w[(long long)b * NN + klist[(long long)gw * LMAX + lane]];
  for (int off = 32; off > 0; off >>= 1) s += __shfl_down(s, off);
  if (lane == 0) {
    float aa = rz[gw] * dnorm[gw] * (s + w[(long long)b * NN + i]);
    aa = aa * aa;
    alpha[(long long)b * NN + i] = 1.f / (1.f + expf(-aa));
  }
}

// ---------- L1 alpha (fp32 A) ----------
__global__ __launch_bounds__(256) void alpha_k(const float* __restrict__ A,
                                               const float* __restrict__ w,
                                               const float* __restrict__ dnorm,
                                               const float* __restrict__ rz,
                                               float* __restrict__ alpha, int R) {
  int gw = (blockIdx.x * 256 + threadIdx.x) >> 6;
  int lane = threadIdx.x & 63;
  int b = gw / R, i = gw - b * R;
  const float4* row = (const float4*)(A + (long long)gw * R);
  const float4* wb4 = (const float4*)(w + (long long)b * R);
  int R4 = R >> 2;
  float s = 0.f;
  for (int j = lane; j < R4; j += 64) {
    float4 a = row[j], ww = wb4[j];
    s += a.x * ww.x + a.y * ww.y + a.z * ww.z + a.w * ww.w;
  }
  for (int off = 32; off > 0; off >>= 1) s += __shfl_down(s, off);
  if (lane == 0) {
    float aa = rz[gw] * dnorm[gw] * (s + w[(long long)b * R + i]);
    aa = aa * aa;
    alpha[(long long)b * NN + i] = 1.f / (1.f + expf(-aa));
  }
}

// ---------- exact k-th largest via radix select ----------
// alpha = sigmoid(x^2) with x real => alpha in [0.5, 1.0] exactly => top byte always 0x3F.
// Round at shift=24 is deterministic (selp=0x3F000000, selr=rank): start at shift=16.
__global__ __launch_bounds__(1024) void topkeep_k(const float* __restrict__ alpha,
                                                  const float* __restrict__ dnorm,
                                                  const float* __restrict__ rz,
                                                  float* __restrict__ colw,
                                                  int* __restrict__ keepidx) {
  __shared__ unsigned vals[NN];
  __shared__ int hist[256];
  __shared__ int wsum[32];
  __shared__ unsigned selp_s;
  __shared__ int selr_s;
  int b = blockIdx.x, t = threadIdx.x;
  vals[t] = __float_as_uint(alpha[b * NN + t]);
  vals[t + 1024] = __float_as_uint(alpha[b * NN + t + 1024]);
  if (t == 0) { selp_s = 0x3F000000u; selr_s = KSEL; }
  __syncthreads();
  for (int shift = 16; shift >= 0; shift -= 8) {
    if (t < 256) hist[t] = 0;
    __syncthreads();
    unsigned pre = selp_s; int rank = selr_s;
    unsigned hm = 0xFFFFFFFFu << (shift + 8);
    for (int e = t; e < NN; e += 1024) {
      unsigned v = vals[e];
      if ((v & hm) == (pre & hm)) atomicAdd(&hist[(v >> shift) & 255], 1);
    }
    __syncthreads();
    for (int off2 = 1; off2 < 256; off2 <<= 1) {
      int v = 0;
      if (t < 256 - off2) v = hist[t + off2];
      __syncthreads();
      if (t < 256 - off2) hist[t] += v;
      __syncthreads();
    }
    if (t < 256) {
      int cge = hist[t];
      int cgt = (t == 255) ? 0 : hist[t + 1];
      if (cge >= rank && cgt < rank) {
        selp_s = pre | ((unsigned)t << shift);
        selr_s = rank - cgt;
      }
    }
    __syncthreads();
  }
  float cu = __uint_as_float(selp_s);
  float a0 = __uint_as_float(vals[t]);
  float a1 = __uint_as_float(vals[t + 1024]);
  float c0 = dnorm[b * NN + t]        * fmaxf(a0 + 1e-7f - cu, 0.f);
  float c1 = dnorm[b * NN + t + 1024] * fmaxf(a1 + 1e-7f - cu, 0.f);
  colw[b * NN + t] = c0;
  colw[b * NN + t + 1024] = c1;
  int f0 = (c0 != 0.f && rz[b * NN + t]        != 0.f) ? 1 : 0;
  int f1 = (c1 != 0.f && rz[b * NN + t + 1024] != 0.f) ? 1 : 0;
  int lane = t & 63, wid = t >> 6;
  unsigned long long m0 = __ballot(f0);
  unsigned long long m1 = __ballot(f1);
  if (lane == 0) { wsum[wid] = __popcll(m0); wsum[16 + wid] = __popcll(m1); }
  __syncthreads();
  if (t == 0) { int run = 0; for (int i2 = 0; i2 < 32; i2++) { int v = wsum[i2]; wsum[i2] = run; run += v; } }
  __syncthreads();
  unsigned long long lm = (1ull << lane) - 1ull;
  int p0 = wsum[wid] + __popcll(m0 & lm);
  int p1 = wsum[16 + wid] + __popcll(m1 & lm);
  if (t < MPAD) keepidx[b * MPAD + t] = -1;
  if (t + 1024 < MPAD) keepidx[b * MPAD + t + 1024] = -1;
  __syncthreads();
  if (f0 && p0 < MPAD) keepidx[b * MPAD + p0] = t;
  if (f1 && p1 < MPAD) keepidx[b * MPAD + p1] = t + 1024;
}

// L1 variant: radix select + compact colw only; pad region (>=MPAD) synthesized as 0.5f
__global__ __launch_bounds__(1024) void topcolw_k(const float* __restrict__ alpha,
                                                  const float* __restrict__ dnorm,
                                                  float* __restrict__ colw) {
  __shared__ unsigned vals[NN];
  __shared__ int hist[256];
  __shared__ unsigned selp_s;
  __shared__ int selr_s;
  int b = blockIdx.x, t = threadIdx.x;
  vals[t] = __float_as_uint(alpha[b * NN + t]);            // t < 1024 < MPAD: always real
  vals[t + 1024] = (t + 1024 >= MPAD) ? __float_as_uint(0.5f)
                                      : __float_as_uint(alpha[b * NN + t + 1024]);
  if (t == 0) { selp_s = 0x3F000000u; selr_s = KSEL; }
  __syncthreads();
  for (int shift = 16; shift >= 0; shift -= 8) {
    if (t < 256) hist[t] = 0;
    __syncthreads();
    unsigned pre = selp_s; int rank = selr_s;
    unsigned hm = 0xFFFFFFFFu << (shift + 8);
    for (int e = t; e < NN; e += 1024) {
      unsigned v = vals[e];
      if ((v & hm) == (pre & hm)) atomicAdd(&hist[(v >> shift) & 255], 1);
    }
    __syncthreads();
    for (int off2 = 1; off2 < 256; off2 <<= 1) {
      int v = 0;
      if (t < 256 - off2) v = hist[t + off2];
      __syncthreads();
      if (t < 256 - off2) hist[t] += v;
      __syncthreads();
    }
    if (t < 256) {
      int cge = hist[t];
      int cgt = (t == 255) ? 0 : hist[t + 1];
      if (cge >= rank && cgt < rank) {
        selp_s = pre | ((unsigned)t << shift);
        selr_s = rank - cgt;
      }
    }
    __syncthreads();
  }
  float cu = __uint_as_float(selp_s);
  for (int ii = t; ii < MPAD; ii += 1024) {
    float c = fmaxf(__uint_as_float(vals[ii]) + 1e-7f - cu, 0.f);
    colw[b * MPAD + ii] = dnorm[b * MPAD + ii] * c;
  }
}

// ---------- L0 scale via nnz gather ----------
__global__ __launch_bounds__(256) void scaleL_k(const ushort_t* __restrict__ klist,
                                                const int* __restrict__ kcnt,
                                                const float* __restrict__ colw,
                                                const float* __restrict__ dnorm,
                                                const float* __restrict__ rz,
                                                float* __restrict__ scale) {
  int gw = (blockIdx.x * 256 + threadIdx.x) >> 6;
  int lane = threadIdx.x & 63;
  int b = gw >> 11, i = gw & (NN - 1);
  int cnt = kcnt[gw];
  float s = 0.f;
  if (lane < cnt) s = colw[(long long)b * NN + klist[(long long)gw * LMAX + lane]];
  for (int off = 32; off > 0; off >>= 1) s += __shfl_down(s, off);
  if (lane == 0) {
    float rsum = rz[gw] * dnorm[gw] * (s + colw[(long long)b * NN + i]);
    scale[gw] = rz[gw] * dnorm[gw] / fmaxf(rsum, 1e-12f);
  }
}

// ---------- L1 scale (fp32 A) ----------
__global__ __launch_bounds__(256) void scale_k(const float* __restrict__ A,
                                               const float* __restrict__ colw,
                                               const float* __restrict__ dnorm,
                                               const float* __restrict__ rz,
                                               float* __restrict__ scale, int R) {
  int gw = (blockIdx.x * 256 + threadIdx.x) >> 6;
  int lane = threadIdx.x & 63;
  int b = gw / R, i = gw - b * R;
  const float4* row = (const float4*)(A + (long long)gw * R);
  const float4* cw4 = (const float4*)(colw + (long long)b * R);
  int R4 = R >> 2;
  float s = 0.f;
  for (int j = lane; j < R4; j += 64) {
    float4 a = row[j], c = cw4[j];
    s += a.x * c.x + a.y * c.y + a.z * c.z + a.w * c.w;
  }
  for (int off = 32; off > 0; off >>= 1) s += __shfl_down(s, off);
  if (lane == 0) {
    float rsum = rz[gw] * dnorm[gw] * (s + colw[(long long)b * R + i]);
    scale[gw] = rz[gw] * dnorm[gw] / fmaxf(rsum, 1e-12f);
  }
}

// ---------- pack per-(b,j) gather programs + cwk ----------
__global__ __launch_bounds__(256) void packlist_k(const ushort_t* __restrict__ klist,
                                                  const int* __restrict__ kcnt,
                                                  const int* __restrict__ keepidx,
                                                  const float* __restrict__ colw,
                                                  ushort_t* __restrict__ klistC,
                                                  int* __restrict__ kcntC,
                                                  float* __restrict__ cwk) {
  int g = blockIdx.x * 256 + threadIdx.x;   // 0..MC-1
  int b = g / MPAD;
  int rj = keepidx[g];
  ushort_t* dst = klistC + (long long)g * LP;
  int cnt = 0;
  if (rj >= 0) {
    long long gr = (long long)b * NN + rj;
    int c = kcnt[gr];
    const ushort_t* src = klist + gr * LMAX;
    for (int t = 0; t < c; t++) dst[t] = src[t];
    dst[c] = (ushort_t)rj;
    cnt = c + 1;
  }
  kcntC[g] = cnt;
  cwk[g] = (rj >= 0) ? colw[b * NN + rj] : 0.f;
  int pad = (cnt + 7) & ~7;
  for (int t = cnt; t < pad; t++) dst[t] = (ushort_t)ZIDX;
}

// ---------- fused sparse R + A2c (scatter, scale, gather; float2-paired planes) ----------
__global__ __launch_bounds__(256) void sparseA2f_k(const ushort_t* __restrict__ klist,
                                                   const int* __restrict__ kcnt,
                                                   const int* __restrict__ keepidx,
                                                   const float* __restrict__ scalev,
                                                   const ushort_t* __restrict__ klistC,
                                                   const int* __restrict__ kcntC,
                                                   const float* __restrict__ cwk,
                                                   float* __restrict__ A2cF,
                                                   ushort_t* __restrict__ A2cH,
                                                   ushort_t* __restrict__ A2cL) {
  __shared__ float Rs[3 * RSTRIDE * 2];   // 3 planes x RSTRIDE float2 = 49,248 B
  int i0 = blockIdx.x * MI;               // MPAD%MI==0 -> no batch straddle
  int b = i0 / MPAD, im0 = i0 - b * MPAD;
  int tid = threadIdx.x;
  int wid = tid >> 6, lane = tid & 63;
  const float* sb = scalev + (long long)b * NN;

  float4 z4 = make_float4(0.f, 0.f, 0.f, 0.f);
  for (int n = tid * 4; n < 3 * RSTRIDE * 2; n += 1024) *(float4*)&Rs[n] = z4;
  __syncthreads();

  for (int rr = wid; rr < MI; rr += 4) {
    int r = keepidx[i0 + rr];
    if (r < 0) continue;
    int p = rr >> 1, q = rr & 1;
    float* plane = Rs + p * RSTRIDE * 2;
    long long gr = (long long)b * NN + r;
    int cr = kcnt[gr];
    int myk = (lane < cr) ? (int)klist[gr * LMAX + lane] : r;
    float mycoef = sb[myk];
    int mycnt = kcnt[(long long)b * NN + myk];
    for (int i = 0; i < cr; i++) {
      int k = __shfl(myk, i);
      float coef = __shfl(mycoef, i);
      int ck = __shfl(mycnt, i);
      if (lane < ck) {
        int n = (int)klist[((long long)b * NN + k) * LMAX + lane];
        plane[n * 2 + q] += coef;
      }
    }
    float coef = sb[r];
    if (lane < cr) plane[myk * 2 + q] += coef;
  }
  __syncthreads();

  for (int c = tid; c < NN; c += 256) {
    float sc = sb[c];
#pragma unroll
    for (int p = 0; p < 3; p++) {
      float2* e = (float2*)&Rs[(p * RSTRIDE + c) * 2];
      float2 v = *e; v.x *= sc; v.y *= sc; *e = v;
    }
  }
  __syncthreads();

  float cwi[MI];
#pragma unroll
  for (int r = 0; r < MI; r++) cwi[r] = cwk[i0 + r];
  long long ob = (long long)b * MPAD * MPAD + (long long)im0 * MPAD;
  for (int j = tid; j < MPAD; j += 256) {
    int cnt = kcntC[b * MPAD + j];
    const ushort_t* kl = klistC + (long long)(b * MPAD + j) * LP;
    float sx0 = 0.f, sy0 = 0.f, sx1 = 0.f, sy1 = 0.f, sx2 = 0.f, sy2 = 0.f;
    int rounds = (cnt + 7) >> 3;
    for (int t0 = 0; t0 < rounds; t0++) {
      uint4 kv = *(const uint4*)(kl + t0 * 8);
      const ushort_t* kp = (const ushort_t*)&kv;
#pragma unroll
      for (int t = 0; t < 8; t++) {
        int c = kp[t];
        float2 v0 = *(const float2*)&Rs[(0 * RSTRIDE + c) * 2];
        float2 v1 = *(const float2*)&Rs[(1 * RSTRIDE + c) * 2];
        float2 v2 = *(const float2*)&Rs[(2 * RSTRIDE + c) * 2];
        sx0 += v0.x; sy0 += v0.y;
        sx1 += v1.x; sy1 += v1.y;
        sx2 += v2.x; sy2 += v2.y;
      }
    }
    float sv[MI] = {sx0, sy0, sx1, sy1, sx2, sy2};
    float cwj = cwk[b * MPAD + j];
#pragma unroll
    for (int r = 0; r < MI; r++) {
      float vq = floorf(cwi[r] * cwj * sv[r] * 10000.f) / 10000.f;
      ushort_t h = f2bf(vq);
      long long o = ob + (long long)r * MPAD + j;
      A2cF[o] = vq;
      A2cH[o] = h;
      A2cL[o] = f2bf(vq - bf2f(h));
    }
  }
}

// ---------- L1 compact S2^T ----------
__global__ void writeS2c_k(const float* __restrict__ A2c, const float* __restrict__ scale,
                           const float* __restrict__ colw,
                           ushort_t* __restrict__ Sh, ushort_t* __restrict__ Sl) {
  int g = blockIdx.x * 256 + threadIdx.x;
  int bl = g / (MPAD / 4);
  int k = (g - bl * (MPAD / 4)) * 4;
  int b = bl / MPAD, l = bl - b * MPAD;
  long long o = (long long)bl * MPAD + k;
  float cw = colw[b * MPAD + l];
  float4 sc = *(const float4*)(scale + b * MPAD + k);
  float4 av = *(const float4*)(A2c + o);
  float v0 = sc.x * (av.x + (float)(k     == l)) * cw;
  float v1 = sc.y * (av.y + (float)(k + 1 == l)) * cw;
  float v2 = sc.z * (av.z + (float)(k + 2 == l)) * cw;
  float v3 = sc.w * (av.w + (float)(k + 3 == l)) * cw;
  ushort_t h0 = f2bf(v0), h1 = f2bf(v1), h2 = f2bf(v2), h3 = f2bf(v3);
  *(uint2*)&Sh[o] = make_uint2((unsigned)h0 | ((unsigned)h1 << 16),
                               (unsigned)h2 | ((unsigned)h3 << 16));
  ushort_t l0 = f2bf(v0 - bf2f(h0)), l1 = f2bf(v1 - bf2f(h1));
  ushort_t l2 = f2bf(v2 - bf2f(h2)), l3 = f2bf(v3 - bf2f(h3));
  *(uint2*)&Sl[o] = make_uint2((unsigned)l0 | ((unsigned)l1 << 16),
                               (unsigned)l2 | ((unsigned)l3 << 16));
}

// ============ MFMA split-bf16 GEMM, batch->XCD swizzled; optional symmetric-output mode ============
template<int SA, int SB, int EPI, int BN, int SYMM>
__global__ __launch_bounds__(256) void mgemm_k(
    const ushort_t* __restrict__ Ah, const ushort_t* __restrict__ Al,
    const ushort_t* __restrict__ Bh, const ushort_t* __restrict__ Bl,
    float* __restrict__ Co, ushort_t* __restrict__ Toh, ushort_t* __restrict__ Tol,
    int M, int Ncol, int K, long long sA, long long sB, long long sC,
    int gx, int ks, long long sPart) {
  constexpr int NJ = BN / 32;            // j-fragments per wave (2 or 4)
  __shared__ ushort_t Ahs[128 * 32];
  __shared__ ushort_t Bhs[BN * 32];
  __shared__ ushort_t Als[SA ? 128 * 32 : 64];
  __shared__ ushort_t Bls[SB ? BN * 32 : 64];

  int tid = threadIdx.x;
  int id = blockIdx.x;
  long long bz = id & 7;
  int rest = id >> 3;
  int kslice = rest % ks;
  int t0 = rest / ks;
  int tm, tn;
  if constexpr (SYMM) {
    tm = 0;
    while ((tm + 1) * (tm + 2) <= t0) tm++;   // base(tm)=tm*(tm+1); row width 2tm+2
    tn = t0 - tm * (tm + 1);
  } else {
    tn = t0 % gx; tm = t0 / gx;
  }
  int n0 = tn * BN, m0 = tm * 128;
  const ushort_t* Ahb = Ah + bz * sA;
  const ushort_t* Alb = SA ? (Al + bz * sA) : Ah;
  const ushort_t* Bhb = Bh + bz * sB;
  const ushort_t* Blb = SB ? (Bl + bz * sB) : Bh;

  int sr = tid >> 2;
  int sc = (tid & 3) * 8;
  int lane = tid & 63, w = tid >> 6;
  int wm = (w >> 1) * 64, wn = (w & 1) * (BN / 2);
  int fr = lane & 15;
  int fo = (lane >> 4) * 8;
  int q = lane >> 4;

  f32x4 acc[4][NJ];
  f32x4 zz = {0.f, 0.f, 0.f, 0.f};
#pragma unroll
  for (int i = 0; i < 4; i++)
#pragma unroll
    for (int j = 0; j < NJ; j++) acc[i][j] = zz;

  int Kpc = K / ks;
  int kbeg = kslice * Kpc;
  for (int k0 = kbeg; k0 < kbeg + Kpc; k0 += 32) {
    __syncthreads();
#pragma unroll
    for (int r = 0; r < 128; r += 64) {
      GLDS16(Ahb + (long long)(m0 + sr + r) * K + k0 + sc, &Ahs[(r + sr) * 32 + sc]);
      if constexpr (SA) {
        GLDS16(Alb + (long long)(m0 + sr + r) * K + k0 + sc, &Als[(r + sr) * 32 + sc]);
      }
    }
#pragma unroll
    for (int r = 0; r < BN; r += 64) {
      GLDS16(Bhb + (long long)(n0 + sr + r) * K + k0 + sc, &Bhs[(r + sr) * 32 + sc]);
      if constexpr (SB) {
        GLDS16(Blb + (long long)(n0 + sr + r) * K + k0 + sc, &Bls[(r + sr) * 32 + sc]);
      }
    }
    __syncthreads();

    short8 ah[4], al[4], bh[NJ], bl[NJ];
#pragma unroll
    for (int i = 0; i < 4; i++) {
      ah[i] = *(const short8*)&Ahs[(wm + i * 16 + fr) * 32 + fo];
      if constexpr (SA) al[i] = *(const short8*)&Als[(wm + i * 16 + fr) * 32 + fo];
    }
#pragma unroll
    for (int j = 0; j < NJ; j++) {
      bh[j] = *(const short8*)&Bhs[(wn + j * 16 + fr) * 32 + fo];
      if constexpr (SB) bl[j] = *(const short8*)&Bls[(wn + j * 16 + fr) * 32 + fo];
    }
#pragma unroll
    for (int i = 0; i < 4; i++)
#pragma unroll
      for (int j = 0; j < NJ; j++) {
        acc[i][j] = __builtin_amdgcn_mfma_f32_16x16x32_bf16(ah[i], bh[j], acc[i][j], 0, 0, 0);
        if constexpr (SB)
          acc[i][j] = __builtin_amdgcn_mfma_f32_16x16x32_bf16(ah[i], bl[j], acc[i][j], 0, 0, 0);
        if constexpr (SA)
          acc[i][j] = __builtin_amdgcn_mfma_f32_16x16x32_bf16(al[i], bh[j], acc[i][j], 0, 0, 0);
      }
  }

#pragma unroll
  for (int i = 0; i < 4; i++)
#pragma unroll
    for (int j = 0; j < NJ; j++)
#pragma unroll
      for (int r = 0; r < 4; r++) {
        float v = acc[i][j][r];
        int row = m0 + wm + i * 16 + q * 4 + r;
        int col = n0 + wn + j * 16 + fr;
        long long idx = bz * sC + (long long)row * Ncol + col;
        if constexpr (EPI == 0) {
          Co[kslice * sPart + idx] = v;
        } else if constexpr (EPI == 1) {
          ushort_t h = f2bf(v);
          Toh[idx] = h;
          Tol[idx] = f2bf(v - bf2f(h));
        } else {  // EPI == 6: quantized fp32 (+ mirror when SYMM strictly-lower tile)
          float vq = floorf(v * 10000.f) / 10000.f;
          Co[idx] = vq;
          if constexpr (SYMM) {
            if (tn < 2 * tm) Co[bz * sC + (long long)col * Ncol + row] = vq;
          }
        }
      }
}

// ---------- final-GCN mean weights: w_l = d_l*(cs_l - d_l*diag_l + d_l), cs = A3 row-dot d ----------
__global__ __launch_bounds__(256) void wfin_k(const float* __restrict__ A3,
                                              const float* __restrict__ dgcn,
                                              const float* __restrict__ diag,
                                              float* __restrict__ wv) {
  int gw = (blockIdx.x * 256 + threadIdx.x) >> 6;   // 0..MC-1
  int lane = threadIdx.x & 63;
  int b = gw / MPAD;
  const float4* row = (const float4*)(A3 + (long long)gw * MPAD);
  const float4* d4 = (const float4*)(dgcn + (long long)b * MPAD);
  float s = 0.f;
  for (int j = lane; j < MPAD / 4; j += 64) {
    float4 a = row[j], d = d4[j];
    s += a.x * d.x + a.y * d.y + a.z * d.z + a.w * d.w;
  }
  for (int off = 32; off > 0; off >>= 1) s += __shfl_down(s, off);
  if (lane == 0) {
    float dl = dgcn[gw];
    wv[gw] = dl * (s - dl * diag[gw] + dl);
  }
}

// ---------- z_k = scale_k*( sum_l A2c[k,l]*colw_l*w_l + colw_k*w_k ) ----------
__global__ __launch_bounds__(256) void zfin_k(const float* __restrict__ A2c,
                                              const float* __restrict__ scalev,
                                              const float* __restrict__ colwv,
                                              const float* __restrict__ wv,
                                              float* __restrict__ zv) {
  int gw = (blockIdx.x * 256 + threadIdx.x) >> 6;   // 0..MC-1
  int lane = threadIdx.x & 63;
  int b = gw / MPAD;
  const float4* row = (const float4*)(A2c + (long long)gw * MPAD);
  const float4* c4 = (const float4*)(colwv + (long long)b * MPAD);
  const float4* w4 = (const float4*)(wv + (long long)b * MPAD);
  float s = 0.f;
  for (int j = lane; j < MPAD / 4; j += 64) {
    float4 a = row[j], c = c4[j], w = w4[j];
    s += a.x * c.x * w.x + a.y * c.y * w.y + a.z * c.z * w.z + a.w * c.w * w.w;
  }
  for (int off = 32; off > 0; off >>= 1) s += __shfl_down(s, off);
  if (lane == 0) {
    zv[gw] = scalev[gw] * (s + colwv[gw] * wv[gw]);
  }
}

// ---------- part[b][c][h] = sum_{r<128} z[b*MPAD+c*128+r] * x2c[...][h] ----------
__global__ void zx_k(const float* __restrict__ zv, const float* __restrict__ x2c,
                     float* __restrict__ part) {
  int b = blockIdx.y, c = blockIdx.x, h = threadIdx.x;   // 128 threads
  const float* p = x2c + ((long long)(b * MPAD + c * 128)) * HH + h;
  const float* zp = zv + b * MPAD + c * 128;
  float s = 0.f;
  for (int r = 0; r < 128; r++) s += zp[r] * p[(long long)r * HH];
  part[(b * 9 + c) * HH + h] = s;
}

// ---------- out2[f] = b2[f] + (1/NN)*sum_h wx3_h*W2[h,f] ----------
__global__ __launch_bounds__(256) void fout2_k(const float* __restrict__ part,
                                               const float* __restrict__ W2,
                                               const float* __restrict__ b2,
                                               float* __restrict__ out) {
  __shared__ float wx3[HH];
  int b = blockIdx.x, f = threadIdx.x;   // 256 threads
  if (f < HH) {
    float s = 0.f;
    for (int c = 0; c < 9; c++) s += part[(b * 9 + c) * HH + f];
    wx3[f] = s;
  }
  __syncthreads();
  float s = 0.f;
  for (int h = 0; h < HH; h++) s += wx3[h] * W2[h * FF + f];
  out[b * (HH + FF) + HH + f] = b2[f] + s * (1.f / NN);
}

// ---------- two-stage column means (GCN1) ----------
__global__ void pmean_k(const float* __restrict__ X, float* __restrict__ part,
                        int Nn, int Fd, int rpc) {
  int b = blockIdx.y, c = blockIdx.x, f = threadIdx.x;
  const float* p = X + ((long long)b * Nn + (long long)c * rpc) * Fd + f;
  float s = 0.f;
  for (int r = 0; r < rpc; r++) s += p[(long long)r * Fd];
  part[((long long)b * gridDim.x + c) * Fd + f] = s;
}

__global__ void fmean_k(const float* __restrict__ part, int nch, int Fd, float corr,
                        const float* __restrict__ bias, float* __restrict__ out, int outoff) {
  int b = blockIdx.x, f = threadIdx.x;
  float s = 0.f;
  for (int c = 0; c < nch; c++) s += part[((long long)b * nch + c) * Fd + f];
  float cv = bias ? corr * bias[f] : 0.f;
  out[b * (HH + FF) + outoff + f] = s * (1.f / NN) + cv;
}

// ---------- fp32 VALU GEMM (GCN1 xw1) ----------
__global__ __launch_bounds__(256) void gemm_k(const float* __restrict__ A, const float* __restrict__ B,
                                              float* __restrict__ C,
                                              int M, int Nw, int Kk,
                                              long long sA, long long sB, long long sC) {
  __shared__ float As[16][128];
  __shared__ float Bs[16][128];
  int tid = threadIdx.x;
  int n0 = blockIdx.x * 128, m0 = blockIdx.y * 128;
  int bz = blockIdx.z;
  const float* Ab = A + (long long)bz * sA;
  const float* Bb = B + (long long)bz * sB;
  float* Cb = C + (long long)bz * sC;
  float acc[8][8];
#pragma unroll
  for (int i = 0; i < 8; i++)
#pragma unroll
    for (int j = 0; j < 8; j++) acc[i][j] = 0.f;
  int tx = tid & 15, ty = tid >> 4;

  for (int k0 = 0; k0 < Kk; k0 += 16) {
    {
      int r = tid >> 2, c = (tid & 3) << 2;
#pragma unroll
      for (int rr = 0; rr < 2; rr++) {
        int rrow = r + rr * 64;
        float4 v = *(const float4*)(Ab + (long long)(m0 + rrow) * Kk + k0 + c);
        As[c + 0][rrow] = v.x; As[c + 1][rrow] = v.y;
        As[c + 2][rrow] = v.z; As[c + 3][rrow] = v.w;
      }
    }
    {
      int kk = tid >> 5, cc = (tid & 31) << 2;
#pragma unroll
      for (int k2 = 0; k2 < 2; k2++) {
        float4 v = *(const float4*)(Bb + (long long)(k0 + kk + k2 * 8) * Nw + n0 + cc);
        *(float4*)&Bs[kk + k2 * 8][cc] = v;
      }
    }
    __syncthreads();
#pragma unroll
    for (int kk = 0; kk < 16; kk++) {
      float a[8], bb[8];
      *(float4*)&a[0]  = *(float4*)&As[kk][ty * 8];
      *(float4*)&a[4]  = *(float4*)&As[kk][ty * 8 + 4];
      *(float4*)&bb[0] = *(float4*)&Bs[kk][tx * 8];
      *(float4*)&bb[4] = *(float4*)&Bs[kk][tx * 8 + 4];
#pragma unroll
      for (int i = 0; i < 8; i++)
#pragma unroll
        for (int j = 0; j < 8; j++) acc[i][j] += a[i] * bb[j];
    }
    __syncthreads();
  }
#pragma unroll
  for (int i = 0; i < 8; i++) {
    float* cp = Cb + (long long)(m0 + ty * 8 + i) * Nw + n0 + tx * 8;
    *(float4*)cp = *(float4*)&acc[i][0];
    *(float4*)(cp + 4) = *(float4*)&acc[i][4];
  }
}

extern "C" void kernel_launch(void* const* d_in, const int* in_sizes, int n_in,
                              void* d_out, int out_size, void* d_ws, size_t ws_size,
                              hipStream_t stream) {
  const float* x    = (const float*)d_in[0];
  const float* adj  = (const float*)d_in[1];
  const float* mask = (const float*)d_in[2];
  const float* W1   = (const float*)d_in[3];
  const float* b1   = (const float*)d_in[4];
  const float* Watt = (const float*)d_in[5];
  const float* batt = (const float*)d_in[6];
  const float* W2   = (const float*)d_in[7];
  const float* b2   = (const float*)d_in[8];
  float* out = (float*)d_out;

  const long long CSTR = (long long)MPAD * NN;
  const long long CTOT = (long long)NB * CSTR;
  const long long M2   = (long long)MPAD * MPAD;
  const long long M2T  = (long long)NB * M2;
  const long long NH   = (long long)NROWS * HH;     // 2,097,152
  const long long MH   = (long long)MC * HH;        // 1,179,648

  // ---- workspace ----
  float* ws = (float*)d_ws;
  long long off = 0;
  ushort_t* S2cH = (ushort_t*)(ws + off); off += M2T;
  float* A2CR = ws + off; off += M2T * 2;
  float* TcF  = ws + off; off += CTOT;
  float* A3F  = ws + off; off += CTOT / 2;   // A3 fp32 (M2T floats; extends into xa, dead by then)
  float* xa   = ws + off; off += NH;
  float* x2c  = ws + off; off += MH;
  float* x3c  = ws + off; off += MH;
  float* diag   = ws + off; off += NROWS;
  float* dgcn   = ws + off; off += NROWS;
  float* dnorm  = ws + off; off += NROWS;
  float* rz     = ws + off; off += NROWS;
  float* wv     = ws + off; off += NROWS;
  float* alphav = ws + off; off += (long long)NB * NN;
  float* colwv  = ws + off; off += NROWS;
  float* scalev = ws + off; off += NROWS;
  off += NROWS / 2;  // (unused)
  off += NROWS / 2;  // (unused)
  int* keepidx  = (int*)(ws + off); off += NB * MPAD;
  float* cwk    = ws + off; off += MC;
  float* partm  = ws + off; off += NB * 16 * FF;

  ushort_t* S2cL = S2cH + M2T;
  float* A2cF = A2CR;
  ushort_t* A2cH = (ushort_t*)(A2CR + M2T);
  ushort_t* A2cL = A2cH + M2T;

  // nnz lists + packed gather programs live in the x3c region
  ushort_t* klist = (ushort_t*)x3c;                  // NROWS*LMAX ushorts
  int* kcnt = (int*)(x3c + (long long)NROWS * (LMAX / 2));
  ushort_t* klistC = (ushort_t*)(x3c + (long long)NROWS * (LMAX / 2) + NROWS);
  int* kcntC = (int*)(x3c + (long long)NROWS * (LMAX / 2) + NROWS + (long long)MC * LP / 2);

  // TcF phase aliases
  float* u1 = TcF;                                   // GCN1 xw1 (NH)
  ushort_t* Tc2H = (ushort_t*)TcF;                   // L1 tmp2 splits (M2T each) [after GCN1]
  ushort_t* Tc2L = Tc2H + M2T;

  // ================= GCN1 (full space, fused sparse acc + epilogue + wvec) =================
  rowstats_k<<<NROWS / 4, 256, 0, stream>>>(adj, klist, kcnt, diag, dgcn, dnorm, rz, NN);
  gemm_k<<<dim3(1, NN / 128, NB), 256, 0, stream>>>(
      x, W1, u1, NN, HH, FF,
      (long long)NN * FF, 0, (long long)NN * HH);
  spmm1e_k<<<NROWS / 4, 256, 0, stream>>>(klist, kcnt, dgcn, diag, b1, mask,
                                          Watt, batt, dnorm, u1, xa, wv);
  pmean_k<<<dim3(16, NB), HH, 0, stream>>>(xa, partm, NN, HH, 128);
  fmean_k<<<NB, HH, 0, stream>>>(partm, 16, HH, 0.f, 0, out, 0);

  // ================= coarsen layer 0 (sparse path) =================
  alphaL_k<<<NROWS / 4, 256, 0, stream>>>(klist, kcnt, wv, dnorm, rz, alphav);
  topkeep_k<<<NB, 1024, 0, stream>>>(alphav, dnorm, rz, colwv, keepidx);
  scaleL_k<<<NROWS / 4, 256, 0, stream>>>(klist, kcnt, colwv, dnorm, rz, scalev);
  packlist_k<<<MC / 256, 256, 0, stream>>>(klist, kcnt, keepidx, colwv, klistC, kcntC, cwk);
  sparseA2f_k<<<MC / MI, 256, 0, stream>>>(klist, kcnt, keepidx, scalev,
                                           klistC, kcntC, cwk, A2cF, A2cH, A2cL);
  spmm2_k<<<MC / 4, 256, 0, stream>>>(klistC, kcntC, scalev, cwk, xa, x2c);

  // ================= coarsen layer 1 (all compact) =================
  rowstatsw_k<<<MC / 4, 256, 0, stream>>>(A2cF, x2c, Watt, batt, dnorm, rz, wv, MPAD);
  alpha_k<<<MC / 4, 256, 0, stream>>>(A2cF, wv, dnorm, rz, alphav, MPAD);
  topcolw_k<<<NB, 1024, 0, stream>>>(alphav, dnorm, colwv);
  scale_k<<<MC / 4, 256, 0, stream>>>(A2cF, colwv, dnorm, rz, scalev, MPAD);
  writeS2c_k<<<(int)(M2T / 4 / 256), 256, 0, stream>>>(A2cF, scalev, colwv, S2cH, S2cL);
  // G1': tmp2^T = S2^T @ A2c, 128x64 tiles (1296 blocks)
  mgemm_k<1, 1, 1, 64, 0><<<(MPAD / 128) * (MPAD / 64) * NB, 256, 0, stream>>>(
      S2cH, S2cL, A2cH, A2cL, 0, Tc2H, Tc2L,
      MPAD, MPAD, MPAD, M2, M2, M2, MPAD / 64, 1, 0);
  // G2': A3 = S2^T @ tmp2 quantized, symmetric: lower-triangle tiles (90x8=720 blocks) + mirror
  mgemm_k<1, 1, 6, 64, 1><<<90 * NB, 256, 0, stream>>>(
      S2cH, S2cL, Tc2H, Tc2L, A3F, 0, 0,
      MPAD, MPAD, MPAD, M2, M2, M2, 0, 1, 0);

  // ================= final GCN mean (fully linear; no GEMMs) =================
  rowstats_k<<<MC / 4, 256, 0, stream>>>(A3F, 0, 0, diag, dgcn, dnorm, rz, MPAD);
  wfin_k<<<MC / 4, 256, 0, stream>>>(A3F, dgcn, diag, wv);
  zfin_k<<<MC / 4, 256, 0, stream>>>(A2cF, scalev, colwv, wv, alphav /*zv*/);
  zx_k<<<dim3(9, NB), HH, 0, stream>>>(alphav, x2c, partm);
  fout2_k<<<NB, FF, 0, stream>>>(partm, W2, b2, out);
}

// Round 14
// 647.290 us; speedup vs baseline: 1.7604x; 1.0110x over previous
//
#include <hip/hip_runtime.h>
#include <math.h>

#define NN 2048
#define NB 8
#define FF 256
#define HH 128
#define KSEL 1025
#define NROWS (NB*NN)
#define MPAD 1152
#define MC (MPAD*NB)
#define LMAX 64
// sparseA2 tiling
#define MI 6
#define RSTRIDE 2052
#define ZIDX 2048
#define LP 72

typedef unsigned short ushort_t;
typedef __attribute__((ext_vector_type(8))) short short8;
typedef __attribute__((ext_vector_type(4))) float f32x4;

__device__ inline ushort_t f2bf(float f) {
  unsigned u = __float_as_uint(f);
  unsigned r = (u + 0x7FFFu + ((u >> 16) & 1u)) >> 16;
  return (ushort_t)r;
}
__device__ inline float bf2f(ushort_t u) {
  unsigned x = ((unsigned)u) << 16;
  return __uint_as_float(x);
}

#define GLDS16(g, l) __builtin_amdgcn_global_load_lds( \
    (const __attribute__((address_space(1))) unsigned int*)(g), \
    (__attribute__((address_space(3))) unsigned int*)(l), 16, 0, 0)

// ---------- row stats + derive fused; optional fused nnz-list extraction ----------
// list positions assigned lane-major (lane l covers cols 4l..4l+3) via ballot prefix.
__global__ __launch_bounds__(256) void rowstats_k(const float* __restrict__ A,
                                                  ushort_t* __restrict__ klist,
                                                  int* __restrict__ kcnt,
                                                  float* __restrict__ diag,
                                                  float* __restrict__ dgcn,
                                                  float* __restrict__ dnorm,
                                                  float* __restrict__ rz, int R) {
  int gw = (blockIdx.x * 256 + threadIdx.x) >> 6;
  int lane = threadIdx.x & 63;
  int b = gw / R, i = gw - b * R;
  const float4* row = (const float4*)(A + (long long)gw * R);
  int R4 = R >> 2;
  float s = 0.f;
  ushort_t* lst = klist ? (klist + (long long)gw * LMAX) : (ushort_t*)0;
  int base = 0;
  unsigned long long lm = (1ull << lane) - 1ull;
  for (int j = lane; j < R4; j += 64) {
    float4 v = row[j];
    s += v.x + v.y + v.z + v.w;
    if (klist) {
      int c0 = (v.x != 0.f), c1 = (v.y != 0.f), c2 = (v.z != 0.f), c3 = (v.w != 0.f);
      unsigned long long m0 = __ballot(c0), m1 = __ballot(c1);
      unsigned long long m2 = __ballot(c2), m3 = __ballot(c3);
      int pre = __popcll(m0 & lm) + __popcll(m1 & lm) + __popcll(m2 & lm) + __popcll(m3 & lm);
      int tot = __popcll(m0) + __popcll(m1) + __popcll(m2) + __popcll(m3);
      int p = base + pre;
      int col = j * 4;
      if (c0) { if (p < LMAX) lst[p] = (ushort_t)col;       p++; }
      if (c1) { if (p < LMAX) lst[p] = (ushort_t)(col + 1); p++; }
      if (c2) { if (p < LMAX) lst[p] = (ushort_t)(col + 2); p++; }
      if (c3) { if (p < LMAX) lst[p] = (ushort_t)(col + 3); p++; }
      base += tot;
    }
  }
  for (int off = 32; off > 0; off >>= 1) s += __shfl_down(s, off);
  if (lane == 0) {
    float dg = A[(long long)gw * R + i];
    diag[gw] = dg;
    dgcn[gw]  = rsqrtf(fmaxf(s - dg + 1.f, 1.f));
    dnorm[gw] = rsqrtf(fmaxf(s + 1.f, 1.f));
    rz[gw]    = s > 0.f ? 1.f : 0.f;
    if (kcnt) kcnt[gw] = base < LMAX ? base : LMAX;
  }
}

// ---------- L1: rowstats + wvec fused (dnorm consumed in-register) ----------
__global__ __launch_bounds__(256) void rowstatsw_k(const float* __restrict__ A,
                                                   const float* __restrict__ X,
                                                   const float* __restrict__ Watt,
                                                   const float* __restrict__ batt,
                                                   float* __restrict__ dnorm,
                                                   float* __restrict__ rz,
                                                   float* __restrict__ w, int R) {
  int gw = (blockIdx.x * 256 + threadIdx.x) >> 6;
  int lane = threadIdx.x & 63;
  int b = gw / R;
  const float4* row = (const float4*)(A + (long long)gw * R);
  int R4 = R >> 2;
  float s = 0.f;
  for (int j = lane; j < R4; j += 64) {
    float4 v = row[j];
    s += v.x + v.y + v.z + v.w;
  }
  for (int off = 32; off > 0; off >>= 1) s += __shfl_xor(s, off);
  float dn = rsqrtf(fmaxf(s + 1.f, 1.f));
  const float* xr = X + (long long)gw * HH;
  float t = xr[lane] * Watt[lane] + xr[lane + 64] * Watt[lane + 64];
  for (int off = 32; off > 0; off >>= 1) t += __shfl_down(t, off);
  if (lane == 0) {
    dnorm[gw] = dn;
    rz[gw]    = s > 0.f ? 1.f : 0.f;
    w[gw] = dn * (t + batt[0]);
  }
}

// ---------- fused GCN1: sparse acc + epilogue (relu/mask) + wvec reduce ----------
__global__ __launch_bounds__(256) void spmm1e_k(const ushort_t* __restrict__ klist,
                                                const int* __restrict__ kcnt,
                                                const float* __restrict__ dgcn,
                                                const float* __restrict__ diag,
                                                const float* __restrict__ b1,
                                                const float* __restrict__ mask,
                                                const float* __restrict__ Watt,
                                                const float* __restrict__ batt,
                                                const float* __restrict__ dnorm,
                                                const float* __restrict__ xw,
                                                float* __restrict__ xa,
                                                float* __restrict__ w) {
  int bid = blockIdx.x;
  int sw = (bid & 7) * ((int)gridDim.x >> 3) + (bid >> 3);
  int gw = (sw * 256 + threadIdx.x) >> 6;
  int lane = threadIdx.x & 63;
  int b = gw >> 11;
  int cnt = kcnt[gw];
  const ushort_t* kl = klist + (long long)gw * LMAX;
  int myk = (lane < cnt) ? (int)kl[lane] : 0;
  float myd = dgcn[b * NN + myk];
  float s0 = 0.f, s1 = 0.f;
  for (int t = 0; t < cnt; t++) {
    int k = __shfl(myk, t);
    float d = __shfl(myd, t);
    const float* xr = xw + ((long long)b * NN + k) * HH;
    s0 += d * xr[lane];
    s1 += d * xr[lane + 64];
  }
  long long o = (long long)gw * HH;
  float d = dgcn[gw];
  float dgv = diag[gw];
  float mv = mask[gw];
  float xw0 = xw[o + lane], xw1v = xw[o + lane + 64];
  float t0 = d * (s0 + (1.f - dgv) * d * xw0) + b1[lane];
  float t1 = d * (s1 + (1.f - dgv) * d * xw1v) + b1[lane + 64];
  t0 *= mv; t1 *= mv;
  float x0 = fmaxf(t0, 0.f), x1 = fmaxf(t1, 0.f);
  xa[o + lane] = x0;
  xa[o + lane + 64] = x1;
  float t = x0 * Watt[lane] + x1 * Watt[lane + 64];
  for (int off = 32; off > 0; off >>= 1) t += __shfl_down(t, off);
  if (lane == 0) w[gw] = dnorm[gw] * (t + batt[0]);
}

// ---------- sparse G3n: x2c[m][f] = cw_m * sum_{k in klistC(m)} scale[k] * x1[b][k][f] ----------
__global__ __launch_bounds__(256) void spmm2_k(const ushort_t* __restrict__ klistC,
                                               const int* __restrict__ kcntC,
                                               const float* __restrict__ scalev,
                                               const float* __restrict__ cwk,
                                               const float* __restrict__ xa,
                                               float* __restrict__ x2c) {
  int bid = blockIdx.x;
  int sw = (bid & 7) * ((int)gridDim.x >> 3) + (bid >> 3);
  int gw = (sw * 256 + threadIdx.x) >> 6;   // 0..MC-1
  int lane = threadIdx.x & 63;
  int b = gw / MPAD;
  int cnt = kcntC[gw];
  const ushort_t* kl = klistC + (long long)gw * LP;
  int c64 = cnt < 64 ? cnt : 64;
  int myk = (lane < c64) ? (int)kl[lane] : 0;
  float myc = scalev[b * NN + myk];
  float s0 = 0.f, s1 = 0.f;
  for (int t = 0; t < c64; t++) {
    int k = __shfl(myk, t);
    float c = __shfl(myc, t);
    const float* xr = xa + ((long long)b * NN + k) * HH;
    s0 += c * xr[lane];
    s1 += c * xr[lane + 64];
  }
  if (cnt > 64) {
    int k = kl[64];
    float c = scalev[b * NN + k];
    const float* xr = xa + ((long long)b * NN + k) * HH;
    s0 += c * xr[lane];
    s1 += c * xr[lane + 64];
  }
  float cw = cwk[gw];
  long long o = (long long)gw * HH;
  x2c[o + lane] = cw * s0;
  x2c[o + lane + 64] = cw * s1;
}

// ---------- L0 alpha via nnz gather ----------
__global__ __launch_bounds__(256) void alphaL_k(const ushort_t* __restrict__ klist,
                                                const int* __restrict__ kcnt,
                                                const float* __restrict__ w,
                                                const float* __restrict__ dnorm,
                                                const float* __restrict__ rz,
                                                float* __restrict__ alpha) {
  int gw = (blockIdx.x * 256 + threadIdx.x) >> 6;
  int lane = threadIdx.x & 63;
  int b = gw >> 11, i = gw & (NN - 1);
  int cnt = kcnt[gw];
  float s = 0.f;
  if (lane < cnt) s = w[(long long)b * NN + klist[(long long)gw * LMAX + lane]];
  for (int off = 32; off > 0; off >>= 1) s += __shfl_down(s, off);
  if (lane == 0) {
    float aa = rz[gw] * dnorm[gw] * (s + w[(long long)b * NN + i]);
    aa = aa * aa;
    alpha[(long long)b * NN + i] = 1.f / (1.f + expf(-aa));
  }
}

// ---------- L1 alpha (fp32 A) ----------
__global__ __launch_bounds__(256) void alpha_k(const float* __restrict__ A,
                                               const float* __restrict__ w,
                                               const float* __restrict__ dnorm,
                                               const float* __restrict__ rz,
                                               float* __restrict__ alpha, int R) {
  int gw = (blockIdx.x * 256 + threadIdx.x) >> 6;
  int lane = threadIdx.x & 63;
  int b = gw / R, i = gw - b * R;
  const float4* row = (const float4*)(A + (long long)gw * R);
  const float4* wb4 = (const float4*)(w + (long long)b * R);
  int R4 = R >> 2;
  float s = 0.f;
  for (int j = lane; j < R4; j += 64) {
    float4 a = row[j], ww = wb4[j];
    s += a.x * ww.x + a.y * ww.y + a.z * ww.z + a.w * ww.w;
  }
  for (int off = 32; off > 0; off >>= 1) s += __shfl_down(s, off);
  if (lane == 0) {
    float aa = rz[gw] * dnorm[gw] * (s + w[(long long)b * R + i]);
    aa = aa * aa;
    alpha[(long long)b * NN + i] = 1.f / (1.f + expf(-aa));
  }
}

// ---------- exact k-th largest via radix select ----------
// alpha = sigmoid(x^2) in [0.5,1.0] => top byte always 0x3F: start at shift=16.
__global__ __launch_bounds__(1024) void topkeep_k(const float* __restrict__ alpha,
                                                  const float* __restrict__ dnorm,
                                                  const float* __restrict__ rz,
                                                  float* __restrict__ colw,
                                                  int* __restrict__ keepidx) {
  __shared__ unsigned vals[NN];
  __shared__ int hist[256];
  __shared__ int wsum[32];
  __shared__ unsigned selp_s;
  __shared__ int selr_s;
  int b = blockIdx.x, t = threadIdx.x;
  vals[t] = __float_as_uint(alpha[b * NN + t]);
  vals[t + 1024] = __float_as_uint(alpha[b * NN + t + 1024]);
  if (t == 0) { selp_s = 0x3F000000u; selr_s = KSEL; }
  __syncthreads();
  for (int shift = 16; shift >= 0; shift -= 8) {
    if (t < 256) hist[t] = 0;
    __syncthreads();
    unsigned pre = selp_s; int rank = selr_s;
    unsigned hm = 0xFFFFFFFFu << (shift + 8);
    for (int e = t; e < NN; e += 1024) {
      unsigned v = vals[e];
      if ((v & hm) == (pre & hm)) atomicAdd(&hist[(v >> shift) & 255], 1);
    }
    __syncthreads();
    for (int off2 = 1; off2 < 256; off2 <<= 1) {
      int v = 0;
      if (t < 256 - off2) v = hist[t + off2];
      __syncthreads();
      if (t < 256 - off2) hist[t] += v;
      __syncthreads();
    }
    if (t < 256) {
      int cge = hist[t];
      int cgt = (t == 255) ? 0 : hist[t + 1];
      if (cge >= rank && cgt < rank) {
        selp_s = pre | ((unsigned)t << shift);
        selr_s = rank - cgt;
      }
    }
    __syncthreads();
  }
  float cu = __uint_as_float(selp_s);
  float a0 = __uint_as_float(vals[t]);
  float a1 = __uint_as_float(vals[t + 1024]);
  float c0 = dnorm[b * NN + t]        * fmaxf(a0 + 1e-7f - cu, 0.f);
  float c1 = dnorm[b * NN + t + 1024] * fmaxf(a1 + 1e-7f - cu, 0.f);
  colw[b * NN + t] = c0;
  colw[b * NN + t + 1024] = c1;
  int f0 = (c0 != 0.f && rz[b * NN + t]        != 0.f) ? 1 : 0;
  int f1 = (c1 != 0.f && rz[b * NN + t + 1024] != 0.f) ? 1 : 0;
  int lane = t & 63, wid = t >> 6;
  unsigned long long m0 = __ballot(f0);
  unsigned long long m1 = __ballot(f1);
  if (lane == 0) { wsum[wid] = __popcll(m0); wsum[16 + wid] = __popcll(m1); }
  __syncthreads();
  if (t == 0) { int run = 0; for (int i2 = 0; i2 < 32; i2++) { int v = wsum[i2]; wsum[i2] = run; run += v; } }
  __syncthreads();
  unsigned long long lm = (1ull << lane) - 1ull;
  int p0 = wsum[wid] + __popcll(m0 & lm);
  int p1 = wsum[16 + wid] + __popcll(m1 & lm);
  if (t < MPAD) keepidx[b * MPAD + t] = -1;
  if (t + 1024 < MPAD) keepidx[b * MPAD + t + 1024] = -1;
  __syncthreads();
  if (f0 && p0 < MPAD) keepidx[b * MPAD + p0] = t;
  if (f1 && p1 < MPAD) keepidx[b * MPAD + p1] = t + 1024;
}

// L1 variant: radix select + compact colw only; pad region (>=MPAD) synthesized as 0.5f
__global__ __launch_bounds__(1024) void topcolw_k(const float* __restrict__ alpha,
                                                  const float* __restrict__ dnorm,
                                                  float* __restrict__ colw) {
  __shared__ unsigned vals[NN];
  __shared__ int hist[256];
  __shared__ unsigned selp_s;
  __shared__ int selr_s;
  int b = blockIdx.x, t = threadIdx.x;
  vals[t] = __float_as_uint(alpha[b * NN + t]);            // t < 1024 < MPAD: always real
  vals[t + 1024] = (t + 1024 >= MPAD) ? __float_as_uint(0.5f)
                                      : __float_as_uint(alpha[b * NN + t + 1024]);
  if (t == 0) { selp_s = 0x3F000000u; selr_s = KSEL; }
  __syncthreads();
  for (int shift = 16; shift >= 0; shift -= 8) {
    if (t < 256) hist[t] = 0;
    __syncthreads();
    unsigned pre = selp_s; int rank = selr_s;
    unsigned hm = 0xFFFFFFFFu << (shift + 8);
    for (int e = t; e < NN; e += 1024) {
      unsigned v = vals[e];
      if ((v & hm) == (pre & hm)) atomicAdd(&hist[(v >> shift) & 255], 1);
    }
    __syncthreads();
    for (int off2 = 1; off2 < 256; off2 <<= 1) {
      int v = 0;
      if (t < 256 - off2) v = hist[t + off2];
      __syncthreads();
      if (t < 256 - off2) hist[t] += v;
      __syncthreads();
    }
    if (t < 256) {
      int cge = hist[t];
      int cgt = (t == 255) ? 0 : hist[t + 1];
      if (cge >= rank && cgt < rank) {
        selp_s = pre | ((unsigned)t << shift);
        selr_s = rank - cgt;
      }
    }
    __syncthreads();
  }
  float cu = __uint_as_float(selp_s);
  for (int ii = t; ii < MPAD; ii += 1024) {
    float c = fmaxf(__uint_as_float(vals[ii]) + 1e-7f - cu, 0.f);
    colw[b * MPAD + ii] = dnorm[b * MPAD + ii] * c;
  }
}

// ---------- L0 scale via nnz gather ----------
__global__ __launch_bounds__(256) void scaleL_k(const ushort_t* __restrict__ klist,
                                                const int* __restrict__ kcnt,
                                                const float* __restrict__ colw,
                                                const float* __restrict__ dnorm,
                                                const float* __restrict__ rz,
                                                float* __restrict__ scale) {
  int gw = (blockIdx.x * 256 + threadIdx.x) >> 6;
  int lane = threadIdx.x & 63;
  int b = gw >> 11, i = gw & (NN - 1);
  int cnt = kcnt[gw];
  float s = 0.f;
  if (lane < cnt) s = colw[(long long)b * NN + klist[(long long)gw * LMAX + lane]];
  for (int off = 32; off > 0; off >>= 1) s += __shfl_down(s, off);
  if (lane == 0) {
    float rsum = rz[gw] * dnorm[gw] * (s + colw[(long long)b * NN + i]);
    scale[gw] = rz[gw] * dnorm[gw] / fmaxf(rsum, 1e-12f);
  }
}

// ---------- L1 scale (fp32 A) ----------
__global__ __launch_bounds__(256) void scale_k(const float* __restrict__ A,
                                               const float* __restrict__ colw,
                                               const float* __restrict__ dnorm,
                                               const float* __restrict__ rz,
                                               float* __restrict__ scale, int R) {
  int gw = (blockIdx.x * 256 + threadIdx.x) >> 6;
  int lane = threadIdx.x & 63;
  int b = gw / R, i = gw - b * R;
  const float4* row = (const float4*)(A + (long long)gw * R);
  const float4* cw4 = (const float4*)(colw + (long long)b * R);
  int R4 = R >> 2;
  float s = 0.f;
  for (int j = lane; j < R4; j += 64) {
    float4 a = row[j], c = cw4[j];
    s += a.x * c.x + a.y * c.y + a.z * c.z + a.w * c.w;
  }
  for (int off = 32; off > 0; off >>= 1) s += __shfl_down(s, off);
  if (lane == 0) {
    float rsum = rz[gw] * dnorm[gw] * (s + colw[(long long)b * R + i]);
    scale[gw] = rz[gw] * dnorm[gw] / fmaxf(rsum, 1e-12f);
  }
}

// ---------- pack per-(b,j) gather programs + cwk ----------
__global__ __launch_bounds__(256) void packlist_k(const ushort_t* __restrict__ klist,
                                                  const int* __restrict__ kcnt,
                                                  const int* __restrict__ keepidx,
                                                  const float* __restrict__ colw,
                                                  ushort_t* __restrict__ klistC,
                                                  int* __restrict__ kcntC,
                                                  float* __restrict__ cwk) {
  int g = blockIdx.x * 256 + threadIdx.x;   // 0..MC-1
  int b = g / MPAD;
  int rj = keepidx[g];
  ushort_t* dst = klistC + (long long)g * LP;
  int cnt = 0;
  if (rj >= 0) {
    long long gr = (long long)b * NN + rj;
    int c = kcnt[gr];
    const ushort_t* src = klist + gr * LMAX;
    for (int t = 0; t < c; t++) dst[t] = src[t];
    dst[c] = (ushort_t)rj;
    cnt = c + 1;
  }
  kcntC[g] = cnt;
  cwk[g] = (rj >= 0) ? colw[b * NN + rj] : 0.f;
  int pad = (cnt + 7) & ~7;
  for (int t = cnt; t < pad; t++) dst[t] = (ushort_t)ZIDX;
}

// ---------- fused sparse R + A2c (scatter, scale, gather; float2-paired planes) ----------
__global__ __launch_bounds__(256) void sparseA2f_k(const ushort_t* __restrict__ klist,
                                                   const int* __restrict__ kcnt,
                                                   const int* __restrict__ keepidx,
                                                   const float* __restrict__ scalev,
                                                   const ushort_t* __restrict__ klistC,
                                                   const int* __restrict__ kcntC,
                                                   const float* __restrict__ cwk,
                                                   float* __restrict__ A2cF,
                                                   ushort_t* __restrict__ A2cH,
                                                   ushort_t* __restrict__ A2cL) {
  __shared__ float Rs[3 * RSTRIDE * 2];   // 3 planes x RSTRIDE float2 = 49,248 B
  int i0 = blockIdx.x * MI;               // MPAD%MI==0 -> no batch straddle
  int b = i0 / MPAD, im0 = i0 - b * MPAD;
  int tid = threadIdx.x;
  int wid = tid >> 6, lane = tid & 63;
  const float* sb = scalev + (long long)b * NN;

  float4 z4 = make_float4(0.f, 0.f, 0.f, 0.f);
  for (int n = tid * 4; n < 3 * RSTRIDE * 2; n += 1024) *(float4*)&Rs[n] = z4;
  __syncthreads();

  for (int rr = wid; rr < MI; rr += 4) {
    int r = keepidx[i0 + rr];
    if (r < 0) continue;
    int p = rr >> 1, q = rr & 1;
    float* plane = Rs + p * RSTRIDE * 2;
    long long gr = (long long)b * NN + r;
    int cr = kcnt[gr];
    int myk = (lane < cr) ? (int)klist[gr * LMAX + lane] : r;
    float mycoef = sb[myk];
    int mycnt = kcnt[(long long)b * NN + myk];
    for (int i = 0; i < cr; i++) {
      int k = __shfl(myk, i);
      float coef = __shfl(mycoef, i);
      int ck = __shfl(mycnt, i);
      if (lane < ck) {
        int n = (int)klist[((long long)b * NN + k) * LMAX + lane];
        plane[n * 2 + q] += coef;
      }
    }
    float coef = sb[r];
    if (lane < cr) plane[myk * 2 + q] += coef;
  }
  __syncthreads();

  for (int c = tid; c < NN; c += 256) {
    float sc = sb[c];
#pragma unroll
    for (int p = 0; p < 3; p++) {
      float2* e = (float2*)&Rs[(p * RSTRIDE + c) * 2];
      float2 v = *e; v.x *= sc; v.y *= sc; *e = v;
    }
  }
  __syncthreads();

  float cwi[MI];
#pragma unroll
  for (int r = 0; r < MI; r++) cwi[r] = cwk[i0 + r];
  long long ob = (long long)b * MPAD * MPAD + (long long)im0 * MPAD;
  for (int j = tid; j < MPAD; j += 256) {
    int cnt = kcntC[b * MPAD + j];
    const ushort_t* kl = klistC + (long long)(b * MPAD + j) * LP;
    float sx0 = 0.f, sy0 = 0.f, sx1 = 0.f, sy1 = 0.f, sx2 = 0.f, sy2 = 0.f;
    int rounds = (cnt + 7) >> 3;
    for (int t0 = 0; t0 < rounds; t0++) {
      uint4 kv = *(const uint4*)(kl + t0 * 8);
      const ushort_t* kp = (const ushort_t*)&kv;
#pragma unroll
      for (int t = 0; t < 8; t++) {
        int c = kp[t];
        float2 v0 = *(const float2*)&Rs[(0 * RSTRIDE + c) * 2];
        float2 v1 = *(const float2*)&Rs[(1 * RSTRIDE + c) * 2];
        float2 v2 = *(const float2*)&Rs[(2 * RSTRIDE + c) * 2];
        sx0 += v0.x; sy0 += v0.y;
        sx1 += v1.x; sy1 += v1.y;
        sx2 += v2.x; sy2 += v2.y;
      }
    }
    float sv[MI] = {sx0, sy0, sx1, sy1, sx2, sy2};
    float cwj = cwk[b * MPAD + j];
#pragma unroll
    for (int r = 0; r < MI; r++) {
      float vq = floorf(cwi[r] * cwj * sv[r] * 10000.f) / 10000.f;
      ushort_t h = f2bf(vq);
      long long o = ob + (long long)r * MPAD + j;
      A2cF[o] = vq;
      A2cH[o] = h;
      A2cL[o] = f2bf(vq - bf2f(h));
    }
  }
}

// ---------- L1 compact S2^T ----------
__global__ void writeS2c_k(const float* __restrict__ A2c, const float* __restrict__ scale,
                           const float* __restrict__ colw,
                           ushort_t* __restrict__ Sh, ushort_t* __restrict__ Sl) {
  int g = blockIdx.x * 256 + threadIdx.x;
  int bl = g / (MPAD / 4);
  int k = (g - bl * (MPAD / 4)) * 4;
  int b = bl / MPAD, l = bl - b * MPAD;
  long long o = (long long)bl * MPAD + k;
  float cw = colw[b * MPAD + l];
  float4 sc = *(const float4*)(scale + b * MPAD + k);
  float4 av = *(const float4*)(A2c + o);
  float v0 = sc.x * (av.x + (float)(k     == l)) * cw;
  float v1 = sc.y * (av.y + (float)(k + 1 == l)) * cw;
  float v2 = sc.z * (av.z + (float)(k + 2 == l)) * cw;
  float v3 = sc.w * (av.w + (float)(k + 3 == l)) * cw;
  ushort_t h0 = f2bf(v0), h1 = f2bf(v1), h2 = f2bf(v2), h3 = f2bf(v3);
  *(uint2*)&Sh[o] = make_uint2((unsigned)h0 | ((unsigned)h1 << 16),
                               (unsigned)h2 | ((unsigned)h3 << 16));
  ushort_t l0 = f2bf(v0 - bf2f(h0)), l1 = f2bf(v1 - bf2f(h1));
  ushort_t l2 = f2bf(v2 - bf2f(h2)), l3 = f2bf(v3 - bf2f(h3));
  *(uint2*)&Sl[o] = make_uint2((unsigned)l0 | ((unsigned)l1 << 16),
                               (unsigned)l2 | ((unsigned)l3 << 16));
}

// ============ MFMA split-bf16 GEMM, batch->XCD swizzled; optional symmetric-output mode ============
template<int SA, int SB, int EPI, int BN, int SYMM>
__global__ __launch_bounds__(256) void mgemm_k(
    const ushort_t* __restrict__ Ah, const ushort_t* __restrict__ Al,
    const ushort_t* __restrict__ Bh, const ushort_t* __restrict__ Bl,
    float* __restrict__ Co, ushort_t* __restrict__ Toh, ushort_t* __restrict__ Tol,
    int M, int Ncol, int K, long long sA, long long sB, long long sC,
    int gx, int ks, long long sPart) {
  constexpr int NJ = BN / 32;            // j-fragments per wave (2 or 4)
  __shared__ ushort_t Ahs[128 * 32];
  __shared__ ushort_t Bhs[BN * 32];
  __shared__ ushort_t Als[SA ? 128 * 32 : 64];
  __shared__ ushort_t Bls[SB ? BN * 32 : 64];

  int tid = threadIdx.x;
  int id = blockIdx.x;
  long long bz = id & 7;
  int rest = id >> 3;
  int kslice = rest % ks;
  int t0 = rest / ks;
  int tm, tn;
  if constexpr (SYMM) {
    tm = 0;
    while ((tm + 1) * (tm + 2) <= t0) tm++;   // base(tm)=tm*(tm+1); row width 2tm+2
    tn = t0 - tm * (tm + 1);
  } else {
    tn = t0 % gx; tm = t0 / gx;
  }
  int n0 = tn * BN, m0 = tm * 128;
  const ushort_t* Ahb = Ah + bz * sA;
  const ushort_t* Alb = SA ? (Al + bz * sA) : Ah;
  const ushort_t* Bhb = Bh + bz * sB;
  const ushort_t* Blb = SB ? (Bl + bz * sB) : Bh;

  int sr = tid >> 2;
  int sc = (tid & 3) * 8;
  int lane = tid & 63, w = tid >> 6;
  int wm = (w >> 1) * 64, wn = (w & 1) * (BN / 2);
  int fr = lane & 15;
  int fo = (lane >> 4) * 8;
  int q = lane >> 4;

  f32x4 acc[4][NJ];
  f32x4 zz = {0.f, 0.f, 0.f, 0.f};
#pragma unroll
  for (int i = 0; i < 4; i++)
#pragma unroll
    for (int j = 0; j < NJ; j++) acc[i][j] = zz;

  int Kpc = K / ks;
  int kbeg = kslice * Kpc;
  for (int k0 = kbeg; k0 < kbeg + Kpc; k0 += 32) {
    __syncthreads();
#pragma unroll
    for (int r = 0; r < 128; r += 64) {
      GLDS16(Ahb + (long long)(m0 + sr + r) * K + k0 + sc, &Ahs[(r + sr) * 32 + sc]);
      if constexpr (SA) {
        GLDS16(Alb + (long long)(m0 + sr + r) * K + k0 + sc, &Als[(r + sr) * 32 + sc]);
      }
    }
#pragma unroll
    for (int r = 0; r < BN; r += 64) {
      GLDS16(Bhb + (long long)(n0 + sr + r) * K + k0 + sc, &Bhs[(r + sr) * 32 + sc]);
      if constexpr (SB) {
        GLDS16(Blb + (long long)(n0 + sr + r) * K + k0 + sc, &Bls[(r + sr) * 32 + sc]);
      }
    }
    __syncthreads();

    short8 ah[4], al[4], bh[NJ], bl[NJ];
#pragma unroll
    for (int i = 0; i < 4; i++) {
      ah[i] = *(const short8*)&Ahs[(wm + i * 16 + fr) * 32 + fo];
      if constexpr (SA) al[i] = *(const short8*)&Als[(wm + i * 16 + fr) * 32 + fo];
    }
#pragma unroll
    for (int j = 0; j < NJ; j++) {
      bh[j] = *(const short8*)&Bhs[(wn + j * 16 + fr) * 32 + fo];
      if constexpr (SB) bl[j] = *(const short8*)&Bls[(wn + j * 16 + fr) * 32 + fo];
    }
#pragma unroll
    for (int i = 0; i < 4; i++)
#pragma unroll
      for (int j = 0; j < NJ; j++) {
        acc[i][j] = __builtin_amdgcn_mfma_f32_16x16x32_bf16(ah[i], bh[j], acc[i][j], 0, 0, 0);
        if constexpr (SB)
          acc[i][j] = __builtin_amdgcn_mfma_f32_16x16x32_bf16(ah[i], bl[j], acc[i][j], 0, 0, 0);
        if constexpr (SA)
          acc[i][j] = __builtin_amdgcn_mfma_f32_16x16x32_bf16(al[i], bh[j], acc[i][j], 0, 0, 0);
      }
  }

#pragma unroll
  for (int i = 0; i < 4; i++)
#pragma unroll
    for (int j = 0; j < NJ; j++)
#pragma unroll
      for (int r = 0; r < 4; r++) {
        float v = acc[i][j][r];
        int row = m0 + wm + i * 16 + q * 4 + r;
        int col = n0 + wn + j * 16 + fr;
        long long idx = bz * sC + (long long)row * Ncol + col;
        if constexpr (EPI == 0) {
          Co[kslice * sPart + idx] = v;
        } else if constexpr (EPI == 1) {
          ushort_t h = f2bf(v);
          Toh[idx] = h;
          Tol[idx] = f2bf(v - bf2f(h));
        } else {  // EPI == 6: quantized fp32 (+ mirror when SYMM strictly-lower tile)
          float vq = floorf(v * 10000.f) / 10000.f;
          Co[idx] = vq;
          if constexpr (SYMM) {
            if (tn < 2 * tm) Co[bz * sC + (long long)col * Ncol + row] = vq;
          }
        }
      }
}

// ---------- final-GCN mean weights: w_l = d_l*(cs_l - d_l*diag_l + d_l), cs = A3 row-dot d ----------
__global__ __launch_bounds__(256) void wfin_k(const float* __restrict__ A3,
                                              const float* __restrict__ dgcn,
                                              const float* __restrict__ diag,
                                              float* __restrict__ wv) {
  int gw = (blockIdx.x * 256 + threadIdx.x) >> 6;   // 0..MC-1
  int lane = threadIdx.x & 63;
  int b = gw / MPAD;
  const float4* row = (const float4*)(A3 + (long long)gw * MPAD);
  const float4* d4 = (const float4*)(dgcn + (long long)b * MPAD);
  float s = 0.f;
  for (int j = lane; j < MPAD / 4; j += 64) {
    float4 a = row[j], d = d4[j];
    s += a.x * d.x + a.y * d.y + a.z * d.z + a.w * d.w;
  }
  for (int off = 32; off > 0; off >>= 1) s += __shfl_down(s, off);
  if (lane == 0) {
    float dl = dgcn[gw];
    wv[gw] = dl * (s - dl * diag[gw] + dl);
  }
}

// ---------- z_k = scale_k*( sum_l A2c[k,l]*colw_l*w_l + colw_k*w_k ) ----------
__global__ __launch_bounds__(256) void zfin_k(const float* __restrict__ A2c,
                                              const float* __restrict__ scalev,
                                              const float* __restrict__ colwv,
                                              const float* __restrict__ wv,
                                              float* __restrict__ zv) {
  int gw = (blockIdx.x * 256 + threadIdx.x) >> 6;   // 0..MC-1
  int lane = threadIdx.x & 63;
  int b = gw / MPAD;
  const float4* row = (const float4*)(A2c + (long long)gw * MPAD);
  const float4* c4 = (const float4*)(colwv + (long long)b * MPAD);
  const float4* w4 = (const float4*)(wv + (long long)b * MPAD);
  float s = 0.f;
  for (int j = lane; j < MPAD / 4; j += 64) {
    float4 a = row[j], c = c4[j], w = w4[j];
    s += a.x * c.x * w.x + a.y * c.y * w.y + a.z * c.z * w.z + a.w * c.w * w.w;
  }
  for (int off = 32; off > 0; off >>= 1) s += __shfl_down(s, off);
  if (lane == 0) {
    zv[gw] = scalev[gw] * (s + colwv[gw] * wv[gw]);
  }
}

// ---------- part[b][c][h] = sum_{r<128} z[b*MPAD+c*128+r] * x2c[...][h] ----------
__global__ void zx_k(const float* __restrict__ zv, const float* __restrict__ x2c,
                     float* __restrict__ part) {
  int b = blockIdx.y, c = blockIdx.x, h = threadIdx.x;   // 128 threads
  const float* p = x2c + ((long long)(b * MPAD + c * 128)) * HH + h;
  const float* zp = zv + b * MPAD + c * 128;
  float s = 0.f;
  for (int r = 0; r < 128; r++) s += zp[r] * p[(long long)r * HH];
  part[(b * 9 + c) * HH + h] = s;
}

// ---------- out2[f] = b2[f] + (1/NN)*sum_h wx3_h*W2[h,f] ----------
__global__ __launch_bounds__(256) void fout2_k(const float* __restrict__ part,
                                               const float* __restrict__ W2,
                                               const float* __restrict__ b2,
                                               float* __restrict__ out) {
  __shared__ float wx3[HH];
  int b = blockIdx.x, f = threadIdx.x;   // 256 threads
  if (f < HH) {
    float s = 0.f;
    for (int c = 0; c < 9; c++) s += part[(b * 9 + c) * HH + f];
    wx3[f] = s;
  }
  __syncthreads();
  float s = 0.f;
  for (int h = 0; h < HH; h++) s += wx3[h] * W2[h * FF + f];
  out[b * (HH + FF) + HH + f] = b2[f] + s * (1.f / NN);
}

// ---------- two-stage column means (GCN1) ----------
__global__ void pmean_k(const float* __restrict__ X, float* __restrict__ part,
                        int Nn, int Fd, int rpc) {
  int b = blockIdx.y, c = blockIdx.x, f = threadIdx.x;
  const float* p = X + ((long long)b * Nn + (long long)c * rpc) * Fd + f;
  float s = 0.f;
  for (int r = 0; r < rpc; r++) s += p[(long long)r * Fd];
  part[((long long)b * gridDim.x + c) * Fd + f] = s;
}

__global__ void fmean_k(const float* __restrict__ part, int nch, int Fd, float corr,
                        const float* __restrict__ bias, float* __restrict__ out, int outoff) {
  int b = blockIdx.x, f = threadIdx.x;
  float s = 0.f;
  for (int c = 0; c < nch; c++) s += part[((long long)b * nch + c) * Fd + f];
  float cv = bias ? corr * bias[f] : 0.f;
  out[b * (HH + FF) + outoff + f] = s * (1.f / NN) + cv;
}

// ---------- fp32 VALU GEMM (GCN1 xw1), 64-row M-tiles: 256 blocks (1/CU) ----------
// Per-output-element FMA order identical to the 128-row version (same k0/kk sequence).
__global__ __launch_bounds__(256) void gemm_k(const float* __restrict__ A, const float* __restrict__ B,
                                              float* __restrict__ C,
                                              int M, int Nw, int Kk,
                                              long long sA, long long sB, long long sC) {
  __shared__ float As[16][64];
  __shared__ float Bs[16][128];
  int tid = threadIdx.x;
  int n0 = blockIdx.x * 128, m0 = blockIdx.y * 64;
  int bz = blockIdx.z;
  const float* Ab = A + (long long)bz * sA;
  const float* Bb = B + (long long)bz * sB;
  float* Cb = C + (long long)bz * sC;
  float acc[4][8];
#pragma unroll
  for (int i = 0; i < 4; i++)
#pragma unroll
    for (int j = 0; j < 8; j++) acc[i][j] = 0.f;
  int tx = tid & 15, ty = tid >> 4;   // ty in [0,16): 4 rows each

  for (int k0 = 0; k0 < Kk; k0 += 16) {
    {
      int r = tid >> 2, c = (tid & 3) << 2;   // 64 rows x 16 k, one float4/thread
      float4 v = *(const float4*)(Ab + (long long)(m0 + r) * Kk + k0 + c);
      As[c + 0][r] = v.x; As[c + 1][r] = v.y;
      As[c + 2][r] = v.z; As[c + 3][r] = v.w;
    }
    {
      int kk = tid >> 5, cc = (tid & 31) << 2;
#pragma unroll
      for (int k2 = 0; k2 < 2; k2++) {
        float4 v = *(const float4*)(Bb + (long long)(k0 + kk + k2 * 8) * Nw + n0 + cc);
        *(float4*)&Bs[kk + k2 * 8][cc] = v;
      }
    }
    __syncthreads();
#pragma unroll
    for (int kk = 0; kk < 16; kk++) {
      float a[4], bb[8];
      *(float4*)&a[0]  = *(float4*)&As[kk][ty * 4];
      *(float4*)&bb[0] = *(float4*)&Bs[kk][tx * 8];
      *(float4*)&bb[4] = *(float4*)&Bs[kk][tx * 8 + 4];
#pragma unroll
      for (int i = 0; i < 4; i++)
#pragma unroll
        for (int j = 0; j < 8; j++) acc[i][j] += a[i] * bb[j];
    }
    __syncthreads();
  }
#pragma unroll
  for (int i = 0; i < 4; i++) {
    float* cp = Cb + (long long)(m0 + ty * 4 + i) * Nw + n0 + tx * 8;
    *(float4*)cp = *(float4*)&acc[i][0];
    *(float4*)(cp + 4) = *(float4*)&acc[i][4];
  }
}

extern "C" void kernel_launch(void* const* d_in, const int* in_sizes, int n_in,
                              void* d_out, int out_size, void* d_ws, size_t ws_size,
                              hipStream_t stream) {
  const float* x    = (const float*)d_in[0];
  const float* adj  = (const float*)d_in[1];
  const float* mask = (const float*)d_in[2];
  const float* W1   = (const float*)d_in[3];
  const float* b1   = (const float*)d_in[4];
  const float* Watt = (const float*)d_in[5];
  const float* batt = (const float*)d_in[6];
  const float* W2   = (const float*)d_in[7];
  const float* b2   = (const float*)d_in[8];
  float* out = (float*)d_out;

  const long long CSTR = (long long)MPAD * NN;
  const long long CTOT = (long long)NB * CSTR;
  const long long M2   = (long long)MPAD * MPAD;
  const long long M2T  = (long long)NB * M2;
  const long long NH   = (long long)NROWS * HH;     // 2,097,152
  const long long MH   = (long long)MC * HH;        // 1,179,648

  // ---- workspace ----
  float* ws = (float*)d_ws;
  long long off = 0;
  ushort_t* S2cH = (ushort_t*)(ws + off); off += M2T;
  float* A2CR = ws + off; off += M2T * 2;
  float* TcF  = ws + off; off += CTOT;
  float* A3F  = ws + off; off += CTOT / 2;   // A3 fp32 (M2T floats; extends into xa, dead by then)
  float* xa   = ws + off; off += NH;
  float* x2c  = ws + off; off += MH;
  float* x3c  = ws + off; off += MH;
  float* diag   = ws + off; off += NROWS;
  float* dgcn   = ws + off; off += NROWS;
  float* dnorm  = ws + off; off += NROWS;
  float* rz     = ws + off; off += NROWS;
  float* wv     = ws + off; off += NROWS;
  float* alphav = ws + off; off += (long long)NB * NN;
  float* colwv  = ws + off; off += NROWS;
  float* scalev = ws + off; off += NROWS;
  off += NROWS / 2;  // (unused)
  off += NROWS / 2;  // (unused)
  int* keepidx  = (int*)(ws + off); off += NB * MPAD;
  float* cwk    = ws + off; off += MC;
  float* partm  = ws + off; off += NB * 16 * FF;

  ushort_t* S2cL = S2cH + M2T;
  float* A2cF = A2CR;
  ushort_t* A2cH = (ushort_t*)(A2CR + M2T);
  ushort_t* A2cL = A2cH + M2T;

  // nnz lists + packed gather programs live in the x3c region
  ushort_t* klist = (ushort_t*)x3c;                  // NROWS*LMAX ushorts
  int* kcnt = (int*)(x3c + (long long)NROWS * (LMAX / 2));
  ushort_t* klistC = (ushort_t*)(x3c + (long long)NROWS * (LMAX / 2) + NROWS);
  int* kcntC = (int*)(x3c + (long long)NROWS * (LMAX / 2) + NROWS + (long long)MC * LP / 2);

  // TcF phase aliases
  float* u1 = TcF;                                   // GCN1 xw1 (NH)
  ushort_t* Tc2H = (ushort_t*)TcF;                   // L1 tmp2 splits (M2T each) [after GCN1]
  ushort_t* Tc2L = Tc2H + M2T;

  // ================= GCN1 (full space, fused sparse acc + epilogue + wvec) =================
  rowstats_k<<<NROWS / 4, 256, 0, stream>>>(adj, klist, kcnt, diag, dgcn, dnorm, rz, NN);
  gemm_k<<<dim3(1, NN / 64, NB), 256, 0, stream>>>(
      x, W1, u1, NN, HH, FF,
      (long long)NN * FF, 0, (long long)NN * HH);
  spmm1e_k<<<NROWS / 4, 256, 0, stream>>>(klist, kcnt, dgcn, diag, b1, mask,
                                          Watt, batt, dnorm, u1, xa, wv);
  pmean_k<<<dim3(16, NB), HH, 0, stream>>>(xa, partm, NN, HH, 128);
  fmean_k<<<NB, HH, 0, stream>>>(partm, 16, HH, 0.f, 0, out, 0);

  // ================= coarsen layer 0 (sparse path) =================
  alphaL_k<<<NROWS / 4, 256, 0, stream>>>(klist, kcnt, wv, dnorm, rz, alphav);
  topkeep_k<<<NB, 1024, 0, stream>>>(alphav, dnorm, rz, colwv, keepidx);
  scaleL_k<<<NROWS / 4, 256, 0, stream>>>(klist, kcnt, colwv, dnorm, rz, scalev);
  packlist_k<<<MC / 256, 256, 0, stream>>>(klist, kcnt, keepidx, colwv, klistC, kcntC, cwk);
  sparseA2f_k<<<MC / MI, 256, 0, stream>>>(klist, kcnt, keepidx, scalev,
                                           klistC, kcntC, cwk, A2cF, A2cH, A2cL);
  spmm2_k<<<MC / 4, 256, 0, stream>>>(klistC, kcntC, scalev, cwk, xa, x2c);

  // ================= coarsen layer 1 (all compact) =================
  rowstatsw_k<<<MC / 4, 256, 0, stream>>>(A2cF, x2c, Watt, batt, dnorm, rz, wv, MPAD);
  alpha_k<<<MC / 4, 256, 0, stream>>>(A2cF, wv, dnorm, rz, alphav, MPAD);
  topcolw_k<<<NB, 1024, 0, stream>>>(alphav, dnorm, colwv);
  scale_k<<<MC / 4, 256, 0, stream>>>(A2cF, colwv, dnorm, rz, scalev, MPAD);
  writeS2c_k<<<(int)(M2T / 4 / 256), 256, 0, stream>>>(A2cF, scalev, colwv, S2cH, S2cL);
  // G1': tmp2^T = S2^T @ A2c, 128x64 tiles (1296 blocks)
  mgemm_k<1, 1, 1, 64, 0><<<(MPAD / 128) * (MPAD / 64) * NB, 256, 0, stream>>>(
      S2cH, S2cL, A2cH, A2cL, 0, Tc2H, Tc2L,
      MPAD, MPAD, MPAD, M2, M2, M2, MPAD / 64, 1, 0);
  // G2': A3 = S2^T @ tmp2 quantized, symmetric: lower-triangle tiles (90x8=720 blocks) + mirror
  mgemm_k<1, 1, 6, 64, 1><<<90 * NB, 256, 0, stream>>>(
      S2cH, S2cL, Tc2H, Tc2L, A3F, 0, 0,
      MPAD, MPAD, MPAD, M2, M2, M2, 0, 1, 0);

  // ================= final GCN mean (fully linear; no GEMMs) =================
  rowstats_k<<<MC / 4, 256, 0, stream>>>(A3F, 0, 0, diag, dgcn, dnorm, rz, MPAD);
  wfin_k<<<MC / 4, 256, 0, stream>>>(A3F, dgcn, diag, wv);
  zfin_k<<<MC / 4, 256, 0, stream>>>(A2cF, scalev, colwv, wv, alphav /*zv*/);
  zx_k<<<dim3(9, NB), HH, 0, stream>>>(alphav, x2c, partm);
  fout2_k<<<NB, FF, 0, stream>>>(partm, W2, b2, out);
}